// Round 1
// baseline (197.455 us; speedup 1.0000x reference)
//
#include <hip/hip_runtime.h>

#define NB 8
#define NT 512
#define NS 512
#define NH 128

__device__ __forceinline__ float fast_tanh(float x) {
  // tanh(x) = 1 - 2/(exp2(x*2*log2 e) + 1); saturates correctly at +-inf
  float e = __builtin_amdgcn_exp2f(x * 2.8853900817779268f);
  return 1.0f - 2.0f * __builtin_amdgcn_rcpf(e + 1.0f);
}

// ---------------- K1: WS = query @ W_s^T, WH = enc @ W_h^T ----------------
// grid 512: blocks [0,256) -> WS, [256,512) -> WH. 16 rows/block, 256 thr.
__global__ __launch_bounds__(256) void bah_proj_kernel(
    const float* __restrict__ query, const float* __restrict__ enc,
    const float* __restrict__ W_s, const float* __restrict__ W_h,
    float* __restrict__ WS, float* __restrict__ WH) {
  __shared__ __align__(16) float lds_in[16 * 128];
  int blk = blockIdx.x;
  const float *in, *W;
  float* out;
  if (blk < 256) { in = query; W = W_s; out = WS; }
  else           { in = enc;   W = W_h; out = WH; blk -= 256; }
  const int r0 = blk * 16;
  for (int i = threadIdx.x; i < 512; i += 256) {   // 16x128 as float4
    int r = i >> 5, c4 = i & 31;
    *(float4*)(lds_in + r * 128 + c4 * 4) =
        *(const float4*)(in + (r0 + r) * NH + c4 * 4);
  }
  __syncthreads();
  const int col = threadIdx.x & 127;
  const int rg  = threadIdx.x >> 7;  // 0/1 -> rows rg*8..rg*8+7
  const float* wp = W + col * NH;    // row `col` of W (L2-resident, 64KB)
  const float* ip = lds_in + rg * 8 * 128;
  float acc[8] = {0.f,0.f,0.f,0.f,0.f,0.f,0.f,0.f};
  #pragma unroll 8
  for (int h4 = 0; h4 < 32; ++h4) {
    float4 w = *(const float4*)(wp + h4 * 4);
    #pragma unroll
    for (int i = 0; i < 8; ++i) {
      float4 x = *(const float4*)(ip + i * 128 + h4 * 4);  // broadcast read
      acc[i] += w.x * x.x + w.y * x.y + w.z * x.z + w.w * x.w;
    }
  }
  #pragma unroll
  for (int i = 0; i < 8; ++i)
    out[(r0 + rg * 8 + i) * NH + col] = acc[i];
}

// -------- K2: fused scores + quirky softmax + ct, per (b, 8 t-rows) --------
// grid 512 = 8 b * 64 t-tiles, 256 threads, ~55KB LDS -> 2 blocks/CU.
__global__ __launch_bounds__(256) void bah_attn_kernel(
    const float* __restrict__ WS, const float* __restrict__ WH,
    const float* __restrict__ v, const float* __restrict__ enc,
    const int* __restrict__ src_len, float* __restrict__ CT) {
  __shared__ __align__(16) float lds_ws[8 * 132];    // pad 132: bank-safe
  __shared__ __align__(16) float lds_wh[64 * 132];   // wh tile / enc tile
  __shared__ __align__(16) float lds_v[128];
  __shared__ __align__(16) float lds_sc[8 * 516];    // scores -> attn
  __shared__ float red[32];

  const int tid = threadIdx.x;
  const int bb = blockIdx.x >> 6;
  const int t0 = (blockIdx.x & 63) * 8;
  const int len = src_len[bb];

  if (tid < 32) *(float4*)(lds_v + tid * 4) = *(const float4*)(v + tid * 4);
  {  // 8x128 ws rows = exactly 256 float4
    int r = tid >> 5, c4 = tid & 31;
    *(float4*)(lds_ws + r * 132 + c4 * 4) =
        *(const float4*)(WS + (bb * NT + t0 + r) * NH + c4 * 4);
  }

  const int t  = tid & 7;    // t-row within tile
  const int sl = tid >> 3;   // 0..31; this thread owns s = s0+sl, s0+sl+32

  // ---- Phase B: scores over 8 s-tiles of 64 ----
  for (int st = 0; st < 8; ++st) {
    const int s0 = st * 64;
    for (int i = tid; i < 2048; i += 256) {   // 64x128 wh tile
      int r = i >> 5, c4 = i & 31;
      *(float4*)(lds_wh + r * 132 + c4 * 4) =
          *(const float4*)(WH + (bb * NS + s0 + r) * NH + c4 * 4);
    }
    __syncthreads();
    const float* wsp  = lds_ws + t * 132;
    const float* whp0 = lds_wh + sl * 132;
    const float* whp1 = lds_wh + (sl + 32) * 132;
    float4 a0 = {0,0,0,0}, a1 = {0,0,0,0};
    #pragma unroll 4
    for (int h4 = 0; h4 < 32; ++h4) {
      float4 w  = *(const float4*)(wsp  + h4 * 4);
      float4 vv = *(const float4*)(lds_v + h4 * 4);
      float4 b0 = *(const float4*)(whp0 + h4 * 4);
      float4 b1 = *(const float4*)(whp1 + h4 * 4);
      a0.x += vv.x * fast_tanh(w.x + b0.x);
      a0.y += vv.y * fast_tanh(w.y + b0.y);
      a0.z += vv.z * fast_tanh(w.z + b0.z);
      a0.w += vv.w * fast_tanh(w.w + b0.w);
      a1.x += vv.x * fast_tanh(w.x + b1.x);
      a1.y += vv.y * fast_tanh(w.y + b1.y);
      a1.z += vv.z * fast_tanh(w.z + b1.z);
      a1.w += vv.w * fast_tanh(w.w + b1.w);
    }
    float s_val0 = (a0.x + a0.y) + (a0.z + a0.w);
    float s_val1 = (a1.x + a1.y) + (a1.z + a1.w);
    int sa = s0 + sl, sb = s0 + sl + 32;
    // faithful quirk: masked scores are ZEROED (still participate in softmax)
    lds_sc[t * 516 + sa] = (sa < len) ? s_val0 : 0.0f;
    lds_sc[t * 516 + sb] = (sb < len) ? s_val1 : 0.0f;
    __syncthreads();
  }

  // ---- Phase C: softmax over S per t-row (t = tid&7, c = tid>>3) ----
  const int c = tid >> 3;       // 0..31, each handles 16 strided s values
  const int wid = tid >> 6;
  float pv[16];
  float mx = -3.4e38f;
  #pragma unroll
  for (int k = 0; k < 16; ++k) {
    pv[k] = lds_sc[t * 516 + c + 32 * k];
    mx = fmaxf(mx, pv[k]);
  }
  #pragma unroll
  for (int msk = 8; msk <= 32; msk <<= 1)
    mx = fmaxf(mx, __shfl_xor(mx, msk, 64));
  if ((tid & 63) < 8) red[wid * 8 + t] = mx;
  __syncthreads();
  mx = fmaxf(fmaxf(red[t], red[8 + t]), fmaxf(red[16 + t], red[24 + t]));
  __syncthreads();
  float sum = 0.f;
  #pragma unroll
  for (int k = 0; k < 16; ++k) {
    pv[k] = __builtin_amdgcn_exp2f((pv[k] - mx) * 1.4426950408889634f);
    sum += pv[k];
  }
  #pragma unroll
  for (int msk = 8; msk <= 32; msk <<= 1)
    sum += __shfl_xor(sum, msk, 64);
  if ((tid & 63) < 8) red[wid * 8 + t] = sum;
  __syncthreads();
  sum = (red[t] + red[8 + t]) + (red[16 + t] + red[24 + t]);
  const float rd = __builtin_amdgcn_rcpf(sum);
  __syncthreads();
  #pragma unroll
  for (int k = 0; k < 16; ++k)
    lds_sc[t * 516 + c + 32 * k] = pv[k] * rd;   // normalized attn
  __syncthreads();

  // ---- Phase D: ct[t][:] = sum_s attn[t][s] * enc[b][s][:] ----
  // 128 active threads: tg = t-pair (4), hg = h/4 group (32); 2t x 4h each
  float4 acc0 = {0,0,0,0}, acc1 = {0,0,0,0};
  const int tg = tid & 3, hg = tid >> 2;  // meaningful for tid<128
  for (int st = 0; st < 8; ++st) {
    const int s0 = st * 64;
    for (int i = tid; i < 2048; i += 256) {   // enc tile reuses lds_wh
      int r = i >> 5, c4 = i & 31;
      *(float4*)(lds_wh + r * 132 + c4 * 4) =
          *(const float4*)(enc + (bb * NS + s0 + r) * NH + c4 * 4);
    }
    __syncthreads();
    if (tid < 128) {
      const float* p0 = lds_sc + (2 * tg) * 516 + s0;
      const float* p1 = lds_sc + (2 * tg + 1) * 516 + s0;
      const float* ep = lds_wh + hg * 4;
      #pragma unroll 4
      for (int s = 0; s < 64; ++s) {
        float4 e = *(const float4*)(ep + s * 132);
        float q0 = p0[s], q1 = p1[s];
        acc0.x += q0 * e.x; acc0.y += q0 * e.y;
        acc0.z += q0 * e.z; acc0.w += q0 * e.w;
        acc1.x += q1 * e.x; acc1.y += q1 * e.y;
        acc1.z += q1 * e.z; acc1.w += q1 * e.w;
      }
    }
    __syncthreads();
  }
  if (tid < 128) {
    int row0 = bb * NT + t0 + 2 * tg;
    *(float4*)(CT + row0 * NH + hg * 4) = acc0;
    *(float4*)(CT + (row0 + 1) * NH + hg * 4) = acc1;
  }
}

// -------- K3: out = tanh([ct, q] @ W_out^T + b) --------
// 256 blocks of 16 rows, 256 threads.
__global__ __launch_bounds__(256) void bah_out_kernel(
    const float* __restrict__ CT, const float* __restrict__ query,
    const float* __restrict__ Wout, const float* __restrict__ bias,
    float* __restrict__ out) {
  __shared__ __align__(16) float lds_in[16 * 256];
  const int r0 = blockIdx.x * 16;
  for (int i = threadIdx.x; i < 1024; i += 256) {  // 16 rows x 256 (ct|q)
    int r = i >> 6, cc = (i & 63) * 4;
    float4 val = (cc < 128)
        ? *(const float4*)(CT + (r0 + r) * NH + cc)
        : *(const float4*)(query + (r0 + r) * NH + cc - 128);
    *(float4*)(lds_in + r * 256 + cc) = val;
  }
  __syncthreads();
  const int col = threadIdx.x & 127;
  const int rg  = threadIdx.x >> 7;
  const float* wp = Wout + col * 256;   // row `col` of W_out (L2-resident)
  const float* ip = lds_in + rg * 8 * 256;
  float acc[8] = {0.f,0.f,0.f,0.f,0.f,0.f,0.f,0.f};
  #pragma unroll 8
  for (int k4 = 0; k4 < 64; ++k4) {
    float4 w = *(const float4*)(wp + k4 * 4);
    #pragma unroll
    for (int i = 0; i < 8; ++i) {
      float4 x = *(const float4*)(ip + i * 256 + k4 * 4);  // broadcast
      acc[i] += w.x * x.x + w.y * x.y + w.z * x.z + w.w * x.w;
    }
  }
  const float bcol = bias[col];
  #pragma unroll
  for (int i = 0; i < 8; ++i)
    out[(r0 + rg * 8 + i) * NH + col] = fast_tanh(acc[i] + bcol);
}

extern "C" void kernel_launch(void* const* d_in, const int* in_sizes, int n_in,
                              void* d_out, int out_size, void* d_ws, size_t ws_size,
                              hipStream_t stream) {
  const float* query = (const float*)d_in[0];
  const float* enc   = (const float*)d_in[1];
  const int*   slen  = (const int*)d_in[2];
  const float* W_h   = (const float*)d_in[3];
  const float* W_s   = (const float*)d_in[4];
  const float* v     = (const float*)d_in[5];
  const float* Woutw = (const float*)d_in[6];
  const float* Woutb = (const float*)d_in[7];
  float* out = (float*)d_out;

  float* ws = (float*)d_ws;
  float* WS = ws;                      // B*T*H = 524288 floats
  float* WH = ws + 524288;             // B*S*H
  float* CT = ws + 1048576;            // B*T*H

  bah_proj_kernel<<<512, 256, 0, stream>>>(query, enc, W_s, W_h, WS, WH);
  bah_attn_kernel<<<512, 256, 0, stream>>>(WS, WH, v, enc, slen, CT);
  bah_out_kernel<<<256, 256, 0, stream>>>(CT, query, Woutw, Woutb, out);
}

// Round 2
// 189.785 us; speedup vs baseline: 1.0404x; 1.0404x over previous
//
#include <hip/hip_runtime.h>

#define NB 8
#define NT 512
#define NS 512
#define NH 128
#define C2LOG2E 2.8853900817779268f   // 2*log2(e): exp2(C*x) = e^(2x)

__device__ __forceinline__ float fast_exp2(float x) { return __builtin_amdgcn_exp2f(x); }
__device__ __forceinline__ float fast_rcp(float x)  { return __builtin_amdgcn_rcpf(x); }
__device__ __forceinline__ float fast_tanh(float x) {
  float e = fast_exp2(x * C2LOG2E);
  return 1.0f - 2.0f * fast_rcp(e + 1.0f);
}

// Paired-h tanh-dot accumulation over a float4 of s values:
//   acc += v0/(e0*f0+1) + v1/(e1*f1+1)  (componentwise over s)
// = (v0*P1 + v1*P0) * rcp(P0*P1); one rcp per TWO h elements.
__device__ __forceinline__ float4 pair_acc(float e0, float e1, float v0, float v1,
                                           float4 f0, float4 f1, float4 acc) {
  float4 P0, P1, num, den;
  P0.x = fmaf(e0, f0.x, 1.0f); P0.y = fmaf(e0, f0.y, 1.0f);
  P0.z = fmaf(e0, f0.z, 1.0f); P0.w = fmaf(e0, f0.w, 1.0f);
  P1.x = fmaf(e1, f1.x, 1.0f); P1.y = fmaf(e1, f1.y, 1.0f);
  P1.z = fmaf(e1, f1.z, 1.0f); P1.w = fmaf(e1, f1.w, 1.0f);
  num.x = fmaf(v0, P1.x, v1 * P0.x); num.y = fmaf(v0, P1.y, v1 * P0.y);
  num.z = fmaf(v0, P1.z, v1 * P0.z); num.w = fmaf(v0, P1.w, v1 * P0.w);
  den.x = P0.x * P1.x; den.y = P0.y * P1.y;
  den.z = P0.z * P1.z; den.w = P0.w * P1.w;
  acc.x = fmaf(num.x, fast_rcp(den.x), acc.x);
  acc.y = fmaf(num.y, fast_rcp(den.y), acc.y);
  acc.z = fmaf(num.z, fast_rcp(den.z), acc.z);
  acc.w = fmaf(num.w, fast_rcp(den.w), acc.w);
  return acc;
}

// ---------------- K1: EWS = exp2(C*(q@W_s^T)) [b][t][h],
//                      EWHT = exp2(C*(enc@W_h^T)) TRANSPOSED [b][h][s] ------
__global__ __launch_bounds__(256) void bah_proj_kernel(
    const float* __restrict__ query, const float* __restrict__ enc,
    const float* __restrict__ W_s, const float* __restrict__ W_h,
    float* __restrict__ EWS, float* __restrict__ EWHT) {
  __shared__ __align__(16) float lds_in[16 * 128];
  int blk = blockIdx.x;
  const bool is_wh = blk >= 256;
  const float* in = is_wh ? enc : query;
  const float* W  = is_wh ? W_h : W_s;
  if (is_wh) blk -= 256;
  const int r0 = blk * 16;
  for (int i = threadIdx.x; i < 512; i += 256) {
    int r = i >> 5, c4 = i & 31;
    *(float4*)(lds_in + r * 128 + c4 * 4) =
        *(const float4*)(in + (r0 + r) * NH + c4 * 4);
  }
  __syncthreads();
  const int cg = (threadIdx.x & 31) * 4;   // 4 cols cg..cg+3
  const int rr = (threadIdx.x >> 5) * 2;   // 2 rows rr, rr+1
  const float* x0 = lds_in + rr * 128;
  const float* x1 = x0 + 128;
  float acc[2][4] = {{0.f,0.f,0.f,0.f},{0.f,0.f,0.f,0.f}};
  for (int h4 = 0; h4 < 32; ++h4) {
    float4 xa = *(const float4*)(x0 + h4 * 4);   // LDS broadcast
    float4 xb = *(const float4*)(x1 + h4 * 4);
    #pragma unroll
    for (int j = 0; j < 4; ++j) {
      float4 w = *(const float4*)(W + (cg + j) * NH + h4 * 4);  // L1-cached
      acc[0][j] += w.x * xa.x + w.y * xa.y + w.z * xa.z + w.w * xa.w;
      acc[1][j] += w.x * xb.x + w.y * xb.y + w.z * xb.z + w.w * xb.w;
    }
  }
  if (!is_wh) {
    #pragma unroll
    for (int i = 0; i < 2; ++i) {
      float4 o;
      o.x = fast_exp2(C2LOG2E * acc[i][0]);
      o.y = fast_exp2(C2LOG2E * acc[i][1]);
      o.z = fast_exp2(C2LOG2E * acc[i][2]);
      o.w = fast_exp2(C2LOG2E * acc[i][3]);
      *(float4*)(EWS + (r0 + rr + i) * NH + cg) = o;
    }
  } else {
    #pragma unroll
    for (int i = 0; i < 2; ++i) {
      int g = r0 + rr + i;
      int b = g >> 9, sl = g & 511;
      #pragma unroll
      for (int j = 0; j < 4; ++j)
        EWHT[b * NH * NS + (cg + j) * NS + sl] = fast_exp2(C2LOG2E * acc[i][j]);
    }
  }
}

// -------- K2: fused scores + quirky softmax + ct, per (b, 8 t-rows) --------
// 256 threads, ~38KB LDS -> 4 blocks/CU target (launch_bounds caps VGPR@128).
__global__ __launch_bounds__(256, 4) void bah_attn_kernel(
    const float* __restrict__ EWS, const float* __restrict__ EWHT,
    const float* __restrict__ v, const float* __restrict__ enc,
    const int* __restrict__ src_len, float* __restrict__ CT) {
  __shared__ __align__(16) float lds_et[8 * 132];
  __shared__ __align__(16) float lds_v[128];
  __shared__ __align__(16) float lds_sc[8 * 516];   // scores; later reduce buf
  __shared__ __align__(16) float lds_aT[512 * 8];   // attn transposed [s][t]
  __shared__ float red[32];

  const int tid = threadIdx.x;
  const int bb = blockIdx.x >> 6;
  const int t0 = (blockIdx.x & 63) * 8;
  const int len = src_len[bb];

  if (tid < 32) *(float4*)(lds_v + tid * 4) = *(const float4*)(v + tid * 4);
  { int r = tid >> 5, c4 = tid & 31;
    *(float4*)(lds_et + r * 132 + c4 * 4) =
        *(const float4*)(EWS + (bb * NT + t0 + r) * NH + c4 * 4); }
  __syncthreads();

  float V0 = 0.f;   // sum of v (all threads redundantly; broadcast reads)
  #pragma unroll
  for (int i = 0; i < 32; ++i) {
    float4 t4 = *(const float4*)(lds_v + i * 4);
    V0 += (t4.x + t4.y) + (t4.z + t4.w);
  }

  // ---- Phase B: scores. thread = (tg: 4 t-rows) x (sp: 4 contiguous s) ----
  const int tg = tid >> 7, sp = tid & 127;
  const float* et = lds_et + tg * 4 * 132;
  const float* fb = EWHT + bb * NH * NS + sp * 4;
  float4 acc4[4] = {{0,0,0,0},{0,0,0,0},{0,0,0,0},{0,0,0,0}};
  for (int ho = 0; ho < 16; ++ho) {
    const float* fh = fb + ho * 8 * NS;
    float4 F0 = *(const float4*)(fh + 0 * NS);   // coalesced global (L2)
    float4 F1 = *(const float4*)(fh + 1 * NS);
    float4 F2 = *(const float4*)(fh + 2 * NS);
    float4 F3 = *(const float4*)(fh + 3 * NS);
    float4 F4 = *(const float4*)(fh + 4 * NS);
    float4 F5 = *(const float4*)(fh + 5 * NS);
    float4 F6 = *(const float4*)(fh + 6 * NS);
    float4 F7 = *(const float4*)(fh + 7 * NS);
    float4 va = *(const float4*)(lds_v + ho * 8);
    float4 vb = *(const float4*)(lds_v + ho * 8 + 4);
    #pragma unroll
    for (int tt = 0; tt < 4; ++tt) {
      float4 e0 = *(const float4*)(et + tt * 132 + ho * 8);      // broadcast
      float4 e1 = *(const float4*)(et + tt * 132 + ho * 8 + 4);
      acc4[tt] = pair_acc(e0.x, e0.y, va.x, va.y, F0, F1, acc4[tt]);
      acc4[tt] = pair_acc(e0.z, e0.w, va.z, va.w, F2, F3, acc4[tt]);
      acc4[tt] = pair_acc(e1.x, e1.y, vb.x, vb.y, F4, F5, acc4[tt]);
      acc4[tt] = pair_acc(e1.z, e1.w, vb.z, vb.w, F6, F7, acc4[tt]);
    }
  }
  const int sbase = sp * 4;
  #pragma unroll
  for (int tt = 0; tt < 4; ++tt) {
    float4 r;   // faithful quirk: masked scores ZEROED, still in softmax
    r.x = (sbase + 0 < len) ? fmaf(-2.f, acc4[tt].x, V0) : 0.f;
    r.y = (sbase + 1 < len) ? fmaf(-2.f, acc4[tt].y, V0) : 0.f;
    r.z = (sbase + 2 < len) ? fmaf(-2.f, acc4[tt].z, V0) : 0.f;
    r.w = (sbase + 3 < len) ? fmaf(-2.f, acc4[tt].w, V0) : 0.f;
    *(float4*)(lds_sc + (tg * 4 + tt) * 516 + sbase) = r;
  }
  __syncthreads();

  // ---- Phase C: softmax per t-row; write attn TRANSPOSED to lds_aT ----
  const int t = tid & 7;
  const int c = tid >> 3;       // 0..31, 16 strided s values each
  const int wid = tid >> 6;
  float pv[16];
  float mx = -3.4e38f;
  #pragma unroll
  for (int k = 0; k < 16; ++k) {
    pv[k] = lds_sc[t * 516 + c + 32 * k];
    mx = fmaxf(mx, pv[k]);
  }
  #pragma unroll
  for (int msk = 8; msk <= 32; msk <<= 1)
    mx = fmaxf(mx, __shfl_xor(mx, msk, 64));
  if ((tid & 63) < 8) red[wid * 8 + t] = mx;
  __syncthreads();
  mx = fmaxf(fmaxf(red[t], red[8 + t]), fmaxf(red[16 + t], red[24 + t]));
  __syncthreads();
  float sum = 0.f;
  #pragma unroll
  for (int k = 0; k < 16; ++k) {
    pv[k] = fast_exp2((pv[k] - mx) * 1.4426950408889634f);
    sum += pv[k];
  }
  #pragma unroll
  for (int msk = 8; msk <= 32; msk <<= 1)
    sum += __shfl_xor(sum, msk, 64);
  if ((tid & 63) < 8) red[wid * 8 + t] = sum;
  __syncthreads();
  sum = (red[t] + red[8 + t]) + (red[16 + t] + red[24 + t]);
  const float rd = fast_rcp(sum);
  #pragma unroll
  for (int k = 0; k < 16; ++k)
    lds_aT[(c + 32 * k) * 8 + t] = pv[k] * rd;
  __syncthreads();

  // ---- Phase D: ct[t][:] += attn[t][s] * enc[s][:], all 256 threads ----
  // thread = (sg: 64 s values) x (hg: 4 h floats); attn via LDS broadcast.
  const int hg = tid & 31, sg = tid >> 5;
  float4 a8[8] = {{0,0,0,0},{0,0,0,0},{0,0,0,0},{0,0,0,0},
                  {0,0,0,0},{0,0,0,0},{0,0,0,0},{0,0,0,0}};
  const float* eb = enc + bb * NS * NH + hg * 4;
  for (int k = 0; k < 64; ++k) {
    int s = sg * 64 + k;
    float4 e  = *(const float4*)(eb + s * NH);        // coalesced global
    float4 w0 = *(const float4*)(lds_aT + s * 8);     // broadcast
    float4 w1 = *(const float4*)(lds_aT + s * 8 + 4);
    a8[0].x += w0.x*e.x; a8[0].y += w0.x*e.y; a8[0].z += w0.x*e.z; a8[0].w += w0.x*e.w;
    a8[1].x += w0.y*e.x; a8[1].y += w0.y*e.y; a8[1].z += w0.y*e.z; a8[1].w += w0.y*e.w;
    a8[2].x += w0.z*e.x; a8[2].y += w0.z*e.y; a8[2].z += w0.z*e.z; a8[2].w += w0.z*e.w;
    a8[3].x += w0.w*e.x; a8[3].y += w0.w*e.y; a8[3].z += w0.w*e.z; a8[3].w += w0.w*e.w;
    a8[4].x += w1.x*e.x; a8[4].y += w1.x*e.y; a8[4].z += w1.x*e.z; a8[4].w += w1.x*e.w;
    a8[5].x += w1.y*e.x; a8[5].y += w1.y*e.y; a8[5].z += w1.y*e.z; a8[5].w += w1.y*e.w;
    a8[6].x += w1.z*e.x; a8[6].y += w1.z*e.y; a8[6].z += w1.z*e.z; a8[6].w += w1.z*e.w;
    a8[7].x += w1.w*e.x; a8[7].y += w1.w*e.y; a8[7].z += w1.w*e.z; a8[7].w += w1.w*e.w;
  }
  #pragma unroll
  for (int i = 0; i < 8; ++i) {   // reduce sg pairs within wave (lane^32)
    a8[i].x += __shfl_xor(a8[i].x, 32, 64);
    a8[i].y += __shfl_xor(a8[i].y, 32, 64);
    a8[i].z += __shfl_xor(a8[i].z, 32, 64);
    a8[i].w += __shfl_xor(a8[i].w, 32, 64);
  }
  float* lred = lds_sc;           // reuse (scores dead)
  const int wv = tid >> 6, lane = tid & 63;
  if (lane < 32) {
    #pragma unroll
    for (int i = 0; i < 8; ++i)
      *(float4*)(lred + wv * 1024 + i * 128 + lane * 4) = a8[i];
  }
  __syncthreads();
  { int tt2 = tid >> 5, hh = tid & 31;
    float4 s0 = *(const float4*)(lred + 0 * 1024 + tt2 * 128 + hh * 4);
    float4 s1 = *(const float4*)(lred + 1 * 1024 + tt2 * 128 + hh * 4);
    float4 s2 = *(const float4*)(lred + 2 * 1024 + tt2 * 128 + hh * 4);
    float4 s3 = *(const float4*)(lred + 3 * 1024 + tt2 * 128 + hh * 4);
    float4 o;
    o.x = (s0.x + s1.x) + (s2.x + s3.x);
    o.y = (s0.y + s1.y) + (s2.y + s3.y);
    o.z = (s0.z + s1.z) + (s2.z + s3.z);
    o.w = (s0.w + s1.w) + (s2.w + s3.w);
    *(float4*)(CT + (bb * NT + t0 + tt2) * NH + hh * 4) = o;
  }
}

// -------- K3: out = tanh([ct, q] @ W_out^T + b) --------
__global__ __launch_bounds__(256) void bah_out_kernel(
    const float* __restrict__ CT, const float* __restrict__ query,
    const float* __restrict__ Wout, const float* __restrict__ bias,
    float* __restrict__ out) {
  __shared__ __align__(16) float lds_in[16 * 256];
  const int r0 = blockIdx.x * 16;
  for (int i = threadIdx.x; i < 1024; i += 256) {
    int r = i >> 6, cc = (i & 63) * 4;
    float4 val = (cc < 128)
        ? *(const float4*)(CT + (r0 + r) * NH + cc)
        : *(const float4*)(query + (r0 + r) * NH + cc - 128);
    *(float4*)(lds_in + r * 256 + cc) = val;
  }
  __syncthreads();
  const int cg = (threadIdx.x & 31) * 4;
  const int rr = (threadIdx.x >> 5) * 2;
  const float* x0 = lds_in + rr * 256;
  const float* x1 = x0 + 256;
  float acc[2][4] = {{0.f,0.f,0.f,0.f},{0.f,0.f,0.f,0.f}};
  for (int k4 = 0; k4 < 64; ++k4) {
    float4 xa = *(const float4*)(x0 + k4 * 4);
    float4 xb = *(const float4*)(x1 + k4 * 4);
    #pragma unroll
    for (int j = 0; j < 4; ++j) {
      float4 w = *(const float4*)(Wout + (cg + j) * 256 + k4 * 4);
      acc[0][j] += w.x * xa.x + w.y * xa.y + w.z * xa.z + w.w * xa.w;
      acc[1][j] += w.x * xb.x + w.y * xb.y + w.z * xb.z + w.w * xb.w;
    }
  }
  float4 bc = *(const float4*)(bias + cg);
  #pragma unroll
  for (int i = 0; i < 2; ++i) {
    float4 o;
    o.x = fast_tanh(acc[i][0] + bc.x);
    o.y = fast_tanh(acc[i][1] + bc.y);
    o.z = fast_tanh(acc[i][2] + bc.z);
    o.w = fast_tanh(acc[i][3] + bc.w);
    *(float4*)(out + (r0 + rr + i) * NH + cg) = o;
  }
}

extern "C" void kernel_launch(void* const* d_in, const int* in_sizes, int n_in,
                              void* d_out, int out_size, void* d_ws, size_t ws_size,
                              hipStream_t stream) {
  const float* query = (const float*)d_in[0];
  const float* enc   = (const float*)d_in[1];
  const int*   slen  = (const int*)d_in[2];
  const float* W_h   = (const float*)d_in[3];
  const float* W_s   = (const float*)d_in[4];
  const float* v     = (const float*)d_in[5];
  const float* Woutw = (const float*)d_in[6];
  const float* Woutb = (const float*)d_in[7];
  float* out = (float*)d_out;

  float* ws = (float*)d_ws;
  float* EWS  = ws;                  // B*T*H
  float* EWHT = ws + 524288;         // B*H*S (transposed)
  float* CT   = ws + 1048576;        // B*T*H

  bah_proj_kernel<<<512, 256, 0, stream>>>(query, enc, W_s, W_h, EWS, EWHT);
  bah_attn_kernel<<<512, 256, 0, stream>>>(EWS, EWHT, v, enc, slen, CT);
  bah_out_kernel<<<256, 256, 0, stream>>>(CT, query, Woutw, Woutb, out);
}

// Round 3
// 140.377 us; speedup vs baseline: 1.4066x; 1.3520x over previous
//
#include <hip/hip_runtime.h>

#define NB 8
#define NT 512
#define NS 512
#define NH 128
#define C2LOG2E 2.8853900817779268f   // 2*log2(e): exp2(C*x) = e^(2x)

__device__ __forceinline__ float fast_exp2(float x) { return __builtin_amdgcn_exp2f(x); }
__device__ __forceinline__ float fast_rcp(float x)  { return __builtin_amdgcn_rcpf(x); }
__device__ __forceinline__ float fast_tanh(float x) {
  float e = fast_exp2(x * C2LOG2E);
  return 1.0f - 2.0f * fast_rcp(e + 1.0f);
}

// acc += v0/(e0*f0+1) + v1/(e1*f1+1) componentwise over 4 s; 1 rcp / 2 elems.
__device__ __forceinline__ float4 pair_acc(float e0, float e1, float v0, float v1,
                                           float4 f0, float4 f1, float4 acc) {
  float4 P0, P1, num, den;
  P0.x = fmaf(e0, f0.x, 1.0f); P0.y = fmaf(e0, f0.y, 1.0f);
  P0.z = fmaf(e0, f0.z, 1.0f); P0.w = fmaf(e0, f0.w, 1.0f);
  P1.x = fmaf(e1, f1.x, 1.0f); P1.y = fmaf(e1, f1.y, 1.0f);
  P1.z = fmaf(e1, f1.z, 1.0f); P1.w = fmaf(e1, f1.w, 1.0f);
  num.x = fmaf(v0, P1.x, v1 * P0.x); num.y = fmaf(v0, P1.y, v1 * P0.y);
  num.z = fmaf(v0, P1.z, v1 * P0.z); num.w = fmaf(v0, P1.w, v1 * P0.w);
  den.x = P0.x * P1.x; den.y = P0.y * P1.y;
  den.z = P0.z * P1.z; den.w = P0.w * P1.w;
  acc.x = fmaf(num.x, fast_rcp(den.x), acc.x);
  acc.y = fmaf(num.y, fast_rcp(den.y), acc.y);
  acc.z = fmaf(num.z, fast_rcp(den.z), acc.z);
  acc.w = fmaf(num.w, fast_rcp(den.w), acc.w);
  return acc;
}

__device__ __forceinline__ float dot4(float4 a, float4 b) {
  return (a.x * b.x + a.y * b.y) + (a.z * b.z + a.w * b.w);
}

// ---------------- K1: EWS = exp2(C*(q@W_s^T)) [b][t][h],
//                      EWHT = exp2(C*(enc@W_h^T)) TRANSPOSED [b][h][s] ------
// W staged in LDS (stride 132: wb bank = (cg+k4)%32, lane-distinct -> free).
// 256 blocks x 32 rows. Thread tile 4 rows x 4 cols (cols strided 32).
__global__ __launch_bounds__(256) void bah_proj_kernel(
    const float* __restrict__ query, const float* __restrict__ enc,
    const float* __restrict__ W_s, const float* __restrict__ W_h,
    float* __restrict__ EWS, float* __restrict__ EWHT) {
  __shared__ __align__(16) float lds_w[128 * 132];   // 66 KB
  __shared__ __align__(16) float lds_x[32 * 132];    // == 128*33 for transpose
  int blk = blockIdx.x;
  const bool is_wh = blk >= 128;
  const float* in = is_wh ? enc : query;
  const float* W  = is_wh ? W_h : W_s;
  if (is_wh) blk -= 128;
  const int r0 = blk * 32;
  const int tid = threadIdx.x;
  for (int i = tid; i < 4096; i += 256) {            // W: 128x32 float4
    int r = i >> 5, c4 = i & 31;
    *(float4*)(lds_w + r * 132 + c4 * 4) = *(const float4*)(W + r * 128 + c4 * 4);
  }
  for (int i = tid; i < 1024; i += 256) {            // x: 32x32 float4
    int r = i >> 5, c4 = i & 31;
    *(float4*)(lds_x + r * 132 + c4 * 4) =
        *(const float4*)(in + (r0 + r) * NH + c4 * 4);
  }
  __syncthreads();
  const int cg = tid & 31;         // cols cg, cg+32, cg+64, cg+96
  const int rg = tid >> 5;         // rows rg*4 .. rg*4+3
  float acc[4][4] = {{0,0,0,0},{0,0,0,0},{0,0,0,0},{0,0,0,0}};
  for (int k4 = 0; k4 < 32; ++k4) {
    float4 xa[4], wb[4];
    #pragma unroll
    for (int i = 0; i < 4; ++i)      // broadcast (wave-uniform addr per half)
      xa[i] = *(const float4*)(lds_x + (rg * 4 + i) * 132 + k4 * 4);
    #pragma unroll
    for (int m = 0; m < 4; ++m)      // bank = (cg+k4)%32 -> conflict-free
      wb[m] = *(const float4*)(lds_w + (cg + 32 * m) * 132 + k4 * 4);
    #pragma unroll
    for (int i = 0; i < 4; ++i)
      #pragma unroll
      for (int m = 0; m < 4; ++m)
        acc[i][m] += dot4(xa[i], wb[m]);
  }
  if (!is_wh) {
    #pragma unroll
    for (int i = 0; i < 4; ++i)
      #pragma unroll
      for (int m = 0; m < 4; ++m)    // lanes cg consecutive -> coalesced
        EWS[(r0 + rg * 4 + i) * NH + cg + 32 * m] =
            fast_exp2(C2LOG2E * acc[i][m]);
  } else {
    __syncthreads();                 // lds_x dead; reuse as 128x33 transpose
    #pragma unroll
    for (int i = 0; i < 4; ++i)
      #pragma unroll
      for (int m = 0; m < 4; ++m)
        lds_x[(cg + 32 * m) * 33 + rg * 4 + i] = fast_exp2(C2LOG2E * acc[i][m]);
    __syncthreads();
    const int b = r0 >> 9, sl0 = r0 & 511;
    const int s_lane = tid & 31, h0 = (tid >> 5) * 16;
    #pragma unroll
    for (int j = 0; j < 16; ++j)     // lanes s consecutive -> coalesced 128B
      EWHT[b * NH * NS + (h0 + j) * NS + sl0 + s_lane] =
          lds_x[(h0 + j) * 33 + s_lane];
  }
}

// -------- K2a: scores only. block = (b, 16 t, 256 s), grid 512 ------------
// thread: tg=tid>>6 (4 t-rows each), sp=tid&63 (4 contiguous s). F amortized
// over 4 t in registers. Fully-masked blocks (len<=s0) zero-fill and exit.
__global__ __launch_bounds__(256) void bah_score_kernel(
    const float* __restrict__ EWS, const float* __restrict__ EWHT,
    const float* __restrict__ v, const int* __restrict__ src_len,
    float* __restrict__ SC) {
  __shared__ __align__(16) float lds_et[16 * 132];
  __shared__ __align__(16) float lds_v[128];
  const int blk = blockIdx.x;
  const int sh = blk & 1, ttile = (blk >> 1) & 31, bb = blk >> 6;
  const int s0 = sh * 256, t0 = ttile * 16;
  const int len = src_len[bb];
  const int tid = threadIdx.x;
  const int tg = tid >> 6, sp = tid & 63;
  const int sbase = s0 + sp * 4;
  float* scb = SC + (bb * NT + t0) * NS;
  if (len <= s0) {                   // block-uniform: whole s-range masked
    float4 z = {0.f, 0.f, 0.f, 0.f};
    #pragma unroll
    for (int tt = 0; tt < 4; ++tt)
      *(float4*)(scb + (tg * 4 + tt) * NS + sbase) = z;
    return;
  }
  if (tid < 32) *(float4*)(lds_v + tid * 4) = *(const float4*)(v + tid * 4);
  for (int i = tid; i < 512; i += 256) {   // 16x128 EWS rows
    int r = i >> 5, c4 = i & 31;
    *(float4*)(lds_et + r * 132 + c4 * 4) =
        *(const float4*)(EWS + (bb * NT + t0 + r) * NH + c4 * 4);
  }
  __syncthreads();
  float V0 = 0.f;
  #pragma unroll
  for (int i = 0; i < 32; ++i) {
    float4 t4 = *(const float4*)(lds_v + i * 4);
    V0 += (t4.x + t4.y) + (t4.z + t4.w);
  }
  const float* et = lds_et + tg * 4 * 132;
  const float* fb = EWHT + bb * NH * NS + sbase;
  float4 acc4[4] = {{0,0,0,0},{0,0,0,0},{0,0,0,0},{0,0,0,0}};
  for (int ho = 0; ho < 16; ++ho) {
    const float* fh = fb + ho * 8 * NS;
    float4 F0 = *(const float4*)(fh + 0 * NS);   // lanes: 64x16B = 1KB coalesced
    float4 F1 = *(const float4*)(fh + 1 * NS);
    float4 F2 = *(const float4*)(fh + 2 * NS);
    float4 F3 = *(const float4*)(fh + 3 * NS);
    float4 F4 = *(const float4*)(fh + 4 * NS);
    float4 F5 = *(const float4*)(fh + 5 * NS);
    float4 F6 = *(const float4*)(fh + 6 * NS);
    float4 F7 = *(const float4*)(fh + 7 * NS);
    float4 va = *(const float4*)(lds_v + ho * 8);
    float4 vb = *(const float4*)(lds_v + ho * 8 + 4);
    #pragma unroll
    for (int tt = 0; tt < 4; ++tt) {
      float4 e0 = *(const float4*)(et + tt * 132 + ho * 8);     // broadcast
      float4 e1 = *(const float4*)(et + tt * 132 + ho * 8 + 4);
      acc4[tt] = pair_acc(e0.x, e0.y, va.x, va.y, F0, F1, acc4[tt]);
      acc4[tt] = pair_acc(e0.z, e0.w, va.z, va.w, F2, F3, acc4[tt]);
      acc4[tt] = pair_acc(e1.x, e1.y, vb.x, vb.y, F4, F5, acc4[tt]);
      acc4[tt] = pair_acc(e1.z, e1.w, vb.z, vb.w, F6, F7, acc4[tt]);
    }
  }
  #pragma unroll
  for (int tt = 0; tt < 4; ++tt) {
    float4 r;   // faithful quirk: masked scores ZEROED, still in softmax
    r.x = (sbase + 0 < len) ? fmaf(-2.f, acc4[tt].x, V0) : 0.f;
    r.y = (sbase + 1 < len) ? fmaf(-2.f, acc4[tt].y, V0) : 0.f;
    r.z = (sbase + 2 < len) ? fmaf(-2.f, acc4[tt].z, V0) : 0.f;
    r.w = (sbase + 3 < len) ? fmaf(-2.f, acc4[tt].w, V0) : 0.f;
    *(float4*)(scb + (tg * 4 + tt) * NS + sbase) = r;
  }
}

// -------- K2b: softmax (quirky) + ct per (b, 8 t-rows), grid 512 ----------
__global__ __launch_bounds__(256) void bah_ctx_kernel(
    const float* __restrict__ SC, const float* __restrict__ enc,
    float* __restrict__ CT) {
  __shared__ __align__(16) float lds_sc[8 * 516];
  __shared__ __align__(16) float lds_aT[512 * 8];
  __shared__ float red[32];
  const int tid = threadIdx.x;
  const int bb = blockIdx.x >> 6;
  const int t0 = (blockIdx.x & 63) * 8;
  for (int i = tid; i < 1024; i += 256) {   // 8x512 scores, coalesced
    int r = i >> 7, c4 = i & 127;
    *(float4*)(lds_sc + r * 516 + c4 * 4) =
        *(const float4*)(SC + (bb * NT + t0 + r) * NS + c4 * 4);
  }
  __syncthreads();

  // ---- softmax per t-row; write attn TRANSPOSED to lds_aT ----
  const int t = tid & 7;
  const int c = tid >> 3;
  const int wid = tid >> 6;
  float pv[16];
  float mx = -3.4e38f;
  #pragma unroll
  for (int k = 0; k < 16; ++k) {
    pv[k] = lds_sc[t * 516 + c + 32 * k];
    mx = fmaxf(mx, pv[k]);
  }
  #pragma unroll
  for (int msk = 8; msk <= 32; msk <<= 1)
    mx = fmaxf(mx, __shfl_xor(mx, msk, 64));
  if ((tid & 63) < 8) red[wid * 8 + t] = mx;
  __syncthreads();
  mx = fmaxf(fmaxf(red[t], red[8 + t]), fmaxf(red[16 + t], red[24 + t]));
  __syncthreads();
  float sum = 0.f;
  #pragma unroll
  for (int k = 0; k < 16; ++k) {
    pv[k] = fast_exp2((pv[k] - mx) * 1.4426950408889634f);
    sum += pv[k];
  }
  #pragma unroll
  for (int msk = 8; msk <= 32; msk <<= 1)
    sum += __shfl_xor(sum, msk, 64);
  if ((tid & 63) < 8) red[wid * 8 + t] = sum;
  __syncthreads();
  sum = (red[t] + red[8 + t]) + (red[16 + t] + red[24 + t]);
  const float rd = fast_rcp(sum);
  #pragma unroll
  for (int k = 0; k < 16; ++k)
    lds_aT[(c + 32 * k) * 8 + t] = pv[k] * rd;
  __syncthreads();

  // ---- ct[t][:] = sum_s attn[t][s] * enc[s][:], all 256 threads ----
  const int hg = tid & 31, sg = tid >> 5;
  float4 a8[8] = {{0,0,0,0},{0,0,0,0},{0,0,0,0},{0,0,0,0},
                  {0,0,0,0},{0,0,0,0},{0,0,0,0},{0,0,0,0}};
  const float* eb = enc + bb * NS * NH + hg * 4;
  for (int k = 0; k < 64; ++k) {
    int s = sg * 64 + k;
    float4 e  = *(const float4*)(eb + s * NH);
    float4 w0 = *(const float4*)(lds_aT + s * 8);
    float4 w1 = *(const float4*)(lds_aT + s * 8 + 4);
    a8[0].x += w0.x*e.x; a8[0].y += w0.x*e.y; a8[0].z += w0.x*e.z; a8[0].w += w0.x*e.w;
    a8[1].x += w0.y*e.x; a8[1].y += w0.y*e.y; a8[1].z += w0.y*e.z; a8[1].w += w0.y*e.w;
    a8[2].x += w0.z*e.x; a8[2].y += w0.z*e.y; a8[2].z += w0.z*e.z; a8[2].w += w0.z*e.w;
    a8[3].x += w0.w*e.x; a8[3].y += w0.w*e.y; a8[3].z += w0.w*e.z; a8[3].w += w0.w*e.w;
    a8[4].x += w1.x*e.x; a8[4].y += w1.x*e.y; a8[4].z += w1.x*e.z; a8[4].w += w1.x*e.w;
    a8[5].x += w1.y*e.x; a8[5].y += w1.y*e.y; a8[5].z += w1.y*e.z; a8[5].w += w1.y*e.w;
    a8[6].x += w1.z*e.x; a8[6].y += w1.z*e.y; a8[6].z += w1.z*e.z; a8[6].w += w1.z*e.w;
    a8[7].x += w1.w*e.x; a8[7].y += w1.w*e.y; a8[7].z += w1.w*e.z; a8[7].w += w1.w*e.w;
  }
  #pragma unroll
  for (int i = 0; i < 8; ++i) {
    a8[i].x += __shfl_xor(a8[i].x, 32, 64);
    a8[i].y += __shfl_xor(a8[i].y, 32, 64);
    a8[i].z += __shfl_xor(a8[i].z, 32, 64);
    a8[i].w += __shfl_xor(a8[i].w, 32, 64);
  }
  float* lred = lds_sc;
  const int wv = tid >> 6, lane = tid & 63;
  if (lane < 32) {
    #pragma unroll
    for (int i = 0; i < 8; ++i)
      *(float4*)(lred + wv * 1024 + i * 128 + lane * 4) = a8[i];
  }
  __syncthreads();
  { int tt2 = tid >> 5, hh = tid & 31;
    float4 s0 = *(const float4*)(lred + 0 * 1024 + tt2 * 128 + hh * 4);
    float4 s1 = *(const float4*)(lred + 1 * 1024 + tt2 * 128 + hh * 4);
    float4 s2 = *(const float4*)(lred + 2 * 1024 + tt2 * 128 + hh * 4);
    float4 s3 = *(const float4*)(lred + 3 * 1024 + tt2 * 128 + hh * 4);
    float4 o;
    o.x = (s0.x + s1.x) + (s2.x + s3.x);
    o.y = (s0.y + s1.y) + (s2.y + s3.y);
    o.z = (s0.z + s1.z) + (s2.z + s3.z);
    o.w = (s0.w + s1.w) + (s2.w + s3.w);
    *(float4*)(CT + (bb * NT + t0 + tt2) * NH + hh * 4) = o;
  }
}

// -------- Fallback fused K2 (round-2, proven) if ws too small for SC ------
__global__ __launch_bounds__(256, 4) void bah_attn_fused(
    const float* __restrict__ EWS, const float* __restrict__ EWHT,
    const float* __restrict__ v, const float* __restrict__ enc,
    const int* __restrict__ src_len, float* __restrict__ CT) {
  __shared__ __align__(16) float lds_et[8 * 132];
  __shared__ __align__(16) float lds_v[128];
  __shared__ __align__(16) float lds_sc[8 * 516];
  __shared__ __align__(16) float lds_aT[512 * 8];
  __shared__ float red[32];
  const int tid = threadIdx.x;
  const int bb = blockIdx.x >> 6;
  const int t0 = (blockIdx.x & 63) * 8;
  const int len = src_len[bb];
  if (tid < 32) *(float4*)(lds_v + tid * 4) = *(const float4*)(v + tid * 4);
  { int r = tid >> 5, c4 = tid & 31;
    *(float4*)(lds_et + r * 132 + c4 * 4) =
        *(const float4*)(EWS + (bb * NT + t0 + r) * NH + c4 * 4); }
  __syncthreads();
  float V0 = 0.f;
  #pragma unroll
  for (int i = 0; i < 32; ++i) {
    float4 t4 = *(const float4*)(lds_v + i * 4);
    V0 += (t4.x + t4.y) + (t4.z + t4.w);
  }
  const int tg = tid >> 7, sp = tid & 127;
  const float* et = lds_et + tg * 4 * 132;
  const float* fb = EWHT + bb * NH * NS + sp * 4;
  float4 acc4[4] = {{0,0,0,0},{0,0,0,0},{0,0,0,0},{0,0,0,0}};
  for (int ho = 0; ho < 16; ++ho) {
    const float* fh = fb + ho * 8 * NS;
    float4 F0 = *(const float4*)(fh + 0 * NS);
    float4 F1 = *(const float4*)(fh + 1 * NS);
    float4 F2 = *(const float4*)(fh + 2 * NS);
    float4 F3 = *(const float4*)(fh + 3 * NS);
    float4 F4 = *(const float4*)(fh + 4 * NS);
    float4 F5 = *(const float4*)(fh + 5 * NS);
    float4 F6 = *(const float4*)(fh + 6 * NS);
    float4 F7 = *(const float4*)(fh + 7 * NS);
    float4 va = *(const float4*)(lds_v + ho * 8);
    float4 vb = *(const float4*)(lds_v + ho * 8 + 4);
    #pragma unroll
    for (int tt = 0; tt < 4; ++tt) {
      float4 e0 = *(const float4*)(et + tt * 132 + ho * 8);
      float4 e1 = *(const float4*)(et + tt * 132 + ho * 8 + 4);
      acc4[tt] = pair_acc(e0.x, e0.y, va.x, va.y, F0, F1, acc4[tt]);
      acc4[tt] = pair_acc(e0.z, e0.w, va.z, va.w, F2, F3, acc4[tt]);
      acc4[tt] = pair_acc(e1.x, e1.y, vb.x, vb.y, F4, F5, acc4[tt]);
      acc4[tt] = pair_acc(e1.z, e1.w, vb.z, vb.w, F6, F7, acc4[tt]);
    }
  }
  const int sbase = sp * 4;
  #pragma unroll
  for (int tt = 0; tt < 4; ++tt) {
    float4 r;
    r.x = (sbase + 0 < len) ? fmaf(-2.f, acc4[tt].x, V0) : 0.f;
    r.y = (sbase + 1 < len) ? fmaf(-2.f, acc4[tt].y, V0) : 0.f;
    r.z = (sbase + 2 < len) ? fmaf(-2.f, acc4[tt].z, V0) : 0.f;
    r.w = (sbase + 3 < len) ? fmaf(-2.f, acc4[tt].w, V0) : 0.f;
    *(float4*)(lds_sc + (tg * 4 + tt) * 516 + sbase) = r;
  }
  __syncthreads();
  const int t = tid & 7;
  const int c = tid >> 3;
  const int wid = tid >> 6;
  float pv[16];
  float mx = -3.4e38f;
  #pragma unroll
  for (int k = 0; k < 16; ++k) {
    pv[k] = lds_sc[t * 516 + c + 32 * k];
    mx = fmaxf(mx, pv[k]);
  }
  #pragma unroll
  for (int msk = 8; msk <= 32; msk <<= 1)
    mx = fmaxf(mx, __shfl_xor(mx, msk, 64));
  if ((tid & 63) < 8) red[wid * 8 + t] = mx;
  __syncthreads();
  mx = fmaxf(fmaxf(red[t], red[8 + t]), fmaxf(red[16 + t], red[24 + t]));
  __syncthreads();
  float sum = 0.f;
  #pragma unroll
  for (int k = 0; k < 16; ++k) {
    pv[k] = fast_exp2((pv[k] - mx) * 1.4426950408889634f);
    sum += pv[k];
  }
  #pragma unroll
  for (int msk = 8; msk <= 32; msk <<= 1)
    sum += __shfl_xor(sum, msk, 64);
  if ((tid & 63) < 8) red[wid * 8 + t] = sum;
  __syncthreads();
  sum = (red[t] + red[8 + t]) + (red[16 + t] + red[24 + t]);
  const float rd = fast_rcp(sum);
  #pragma unroll
  for (int k = 0; k < 16; ++k)
    lds_aT[(c + 32 * k) * 8 + t] = pv[k] * rd;
  __syncthreads();
  const int hg = tid & 31, sg = tid >> 5;
  float4 a8[8] = {{0,0,0,0},{0,0,0,0},{0,0,0,0},{0,0,0,0},
                  {0,0,0,0},{0,0,0,0},{0,0,0,0},{0,0,0,0}};
  const float* eb = enc + bb * NS * NH + hg * 4;
  for (int k = 0; k < 64; ++k) {
    int s = sg * 64 + k;
    float4 e  = *(const float4*)(eb + s * NH);
    float4 w0 = *(const float4*)(lds_aT + s * 8);
    float4 w1 = *(const float4*)(lds_aT + s * 8 + 4);
    a8[0].x += w0.x*e.x; a8[0].y += w0.x*e.y; a8[0].z += w0.x*e.z; a8[0].w += w0.x*e.w;
    a8[1].x += w0.y*e.x; a8[1].y += w0.y*e.y; a8[1].z += w0.y*e.z; a8[1].w += w0.y*e.w;
    a8[2].x += w0.z*e.x; a8[2].y += w0.z*e.y; a8[2].z += w0.z*e.z; a8[2].w += w0.z*e.w;
    a8[3].x += w0.w*e.x; a8[3].y += w0.w*e.y; a8[3].z += w0.w*e.z; a8[3].w += w0.w*e.w;
    a8[4].x += w1.x*e.x; a8[4].y += w1.x*e.y; a8[4].z += w1.x*e.z; a8[4].w += w1.x*e.w;
    a8[5].x += w1.y*e.x; a8[5].y += w1.y*e.y; a8[5].z += w1.y*e.z; a8[5].w += w1.y*e.w;
    a8[6].x += w1.z*e.x; a8[6].y += w1.z*e.y; a8[6].z += w1.z*e.z; a8[6].w += w1.z*e.w;
    a8[7].x += w1.w*e.x; a8[7].y += w1.w*e.y; a8[7].z += w1.w*e.z; a8[7].w += w1.w*e.w;
  }
  #pragma unroll
  for (int i = 0; i < 8; ++i) {
    a8[i].x += __shfl_xor(a8[i].x, 32, 64);
    a8[i].y += __shfl_xor(a8[i].y, 32, 64);
    a8[i].z += __shfl_xor(a8[i].z, 32, 64);
    a8[i].w += __shfl_xor(a8[i].w, 32, 64);
  }
  float* lred = lds_sc;
  const int wv = tid >> 6, lane = tid & 63;
  if (lane < 32) {
    #pragma unroll
    for (int i = 0; i < 8; ++i)
      *(float4*)(lred + wv * 1024 + i * 128 + lane * 4) = a8[i];
  }
  __syncthreads();
  { int tt2 = tid >> 5, hh = tid & 31;
    float4 s0 = *(const float4*)(lred + 0 * 1024 + tt2 * 128 + hh * 4);
    float4 s1 = *(const float4*)(lred + 1 * 1024 + tt2 * 128 + hh * 4);
    float4 s2 = *(const float4*)(lred + 2 * 1024 + tt2 * 128 + hh * 4);
    float4 s3 = *(const float4*)(lred + 3 * 1024 + tt2 * 128 + hh * 4);
    float4 o;
    o.x = (s0.x + s1.x) + (s2.x + s3.x);
    o.y = (s0.y + s1.y) + (s2.y + s3.y);
    o.z = (s0.z + s1.z) + (s2.z + s3.z);
    o.w = (s0.w + s1.w) + (s2.w + s3.w);
    *(float4*)(CT + (bb * NT + t0 + tt2) * NH + hh * 4) = o;
  }
}

// -------- K3: out = tanh([ct, q] @ W_out^T + b), LDS-staged W (2 K-passes) -
__global__ __launch_bounds__(256) void bah_out_kernel(
    const float* __restrict__ CT, const float* __restrict__ query,
    const float* __restrict__ Wout, const float* __restrict__ bias,
    float* __restrict__ out) {
  __shared__ __align__(16) float lds_w[128 * 132];   // one K-half of Wout
  __shared__ __align__(16) float lds_x[16 * 260];    // [ct|q] rows
  const int r0 = blockIdx.x * 16;
  const int tid = threadIdx.x;
  for (int i = tid; i < 1024; i += 256) {    // 16 rows x 64 float4 (ct|q)
    int r = i >> 6, cc = (i & 63) * 4;
    float4 val = (cc < 128)
        ? *(const float4*)(CT + (r0 + r) * NH + cc)
        : *(const float4*)(query + (r0 + r) * NH + cc - 128);
    *(float4*)(lds_x + r * 260 + cc) = val;
  }
  const int cg = tid & 31;       // cols cg, cg+32, cg+64, cg+96
  const int rg = tid >> 5;       // rows rg*2, rg*2+1
  float acc[2][4] = {{0,0,0,0},{0,0,0,0}};
  for (int p = 0; p < 2; ++p) {
    __syncthreads();             // protect lds_w reload (and initial x stage)
    for (int i = tid; i < 4096; i += 256) {  // Wout[:, p*128 .. p*128+127]
      int r = i >> 5, c4 = i & 31;
      *(float4*)(lds_w + r * 132 + c4 * 4) =
          *(const float4*)(Wout + r * 256 + p * 128 + c4 * 4);
    }
    __syncthreads();
    for (int k4 = 0; k4 < 32; ++k4) {
      float4 xa[2], wb[4];
      #pragma unroll
      for (int i = 0; i < 2; ++i)
        xa[i] = *(const float4*)(lds_x + (rg * 2 + i) * 260 + p * 128 + k4 * 4);
      #pragma unroll
      for (int m = 0; m < 4; ++m)
        wb[m] = *(const float4*)(lds_w + (cg + 32 * m) * 132 + k4 * 4);
      #pragma unroll
      for (int i = 0; i < 2; ++i)
        #pragma unroll
        for (int m = 0; m < 4; ++m)
          acc[i][m] += dot4(xa[i], wb[m]);
    }
  }
  #pragma unroll
  for (int i = 0; i < 2; ++i)
    #pragma unroll
    for (int m = 0; m < 4; ++m)
      out[(r0 + rg * 2 + i) * NH + cg + 32 * m] =
          fast_tanh(acc[i][m] + bias[cg + 32 * m]);
}

extern "C" void kernel_launch(void* const* d_in, const int* in_sizes, int n_in,
                              void* d_out, int out_size, void* d_ws, size_t ws_size,
                              hipStream_t stream) {
  const float* query = (const float*)d_in[0];
  const float* enc   = (const float*)d_in[1];
  const int*   slen  = (const int*)d_in[2];
  const float* W_h   = (const float*)d_in[3];
  const float* W_s   = (const float*)d_in[4];
  const float* v     = (const float*)d_in[5];
  const float* Woutw = (const float*)d_in[6];
  const float* Woutb = (const float*)d_in[7];
  float* out = (float*)d_out;

  float* ws = (float*)d_ws;
  float* EWS  = ws;                  // B*T*H   = 524288 floats (2 MB)
  float* EWHT = ws + 524288;         // B*H*S   (transposed, 2 MB)
  float* CT   = ws + 1048576;        // B*T*H   (2 MB)
  float* SC   = ws + 1572864;        // B*T*S   = 2097152 floats (8 MB)
  const bool have_sc = ws_size >= (size_t)(1572864 + 2097152) * sizeof(float);

  bah_proj_kernel<<<256, 256, 0, stream>>>(query, enc, W_s, W_h, EWS, EWHT);
  if (have_sc) {
    bah_score_kernel<<<512, 256, 0, stream>>>(EWS, EWHT, v, slen, SC);
    bah_ctx_kernel<<<512, 256, 0, stream>>>(SC, enc, CT);
  } else {
    bah_attn_fused<<<512, 256, 0, stream>>>(EWS, EWHT, v, enc, slen, CT);
  }
  bah_out_kernel<<<256, 256, 0, stream>>>(CT, query, Woutw, Woutb, out);
}

// Round 4
// 135.057 us; speedup vs baseline: 1.4620x; 1.0394x over previous
//
#include <hip/hip_runtime.h>

#define NB 8
#define NT 512
#define NS 512
#define NH 128
#define C2LOG2E 2.8853900817779268f   // 2*log2(e): exp2(C*x) = e^(2x)

__device__ __forceinline__ float fast_exp2(float x) { return __builtin_amdgcn_exp2f(x); }
__device__ __forceinline__ float fast_rcp(float x)  { return __builtin_amdgcn_rcpf(x); }
__device__ __forceinline__ float fast_tanh(float x) {
  float e = fast_exp2(x * C2LOG2E);
  return 1.0f - 2.0f * fast_rcp(e + 1.0f);
}

__device__ __forceinline__ float dot4(float4 a, float4 b) {
  return (a.x * b.x + a.y * b.y) + (a.z * b.z + a.w * b.w);
}

// acc += v0/(e0*f0+1) + v1/(e1*f1+1) over 2 s values; 1 rcp per 2 h-elems.
__device__ __forceinline__ float2 pair_acc2(float e0, float e1, float v0, float v1,
                                            float2 f0, float2 f1, float2 acc) {
  float2 P0, P1, num, den;
  P0.x = fmaf(e0, f0.x, 1.0f); P0.y = fmaf(e0, f0.y, 1.0f);
  P1.x = fmaf(e1, f1.x, 1.0f); P1.y = fmaf(e1, f1.y, 1.0f);
  num.x = fmaf(v0, P1.x, v1 * P0.x); num.y = fmaf(v0, P1.y, v1 * P0.y);
  den.x = P0.x * P1.x; den.y = P0.y * P1.y;
  acc.x = fmaf(num.x, fast_rcp(den.x), acc.x);
  acc.y = fmaf(num.y, fast_rcp(den.y), acc.y);
  return acc;
}

// float4 variant for the fused fallback kernel.
__device__ __forceinline__ float4 pair_acc(float e0, float e1, float v0, float v1,
                                           float4 f0, float4 f1, float4 acc) {
  float4 P0, P1, num, den;
  P0.x = fmaf(e0, f0.x, 1.0f); P0.y = fmaf(e0, f0.y, 1.0f);
  P0.z = fmaf(e0, f0.z, 1.0f); P0.w = fmaf(e0, f0.w, 1.0f);
  P1.x = fmaf(e1, f1.x, 1.0f); P1.y = fmaf(e1, f1.y, 1.0f);
  P1.z = fmaf(e1, f1.z, 1.0f); P1.w = fmaf(e1, f1.w, 1.0f);
  num.x = fmaf(v0, P1.x, v1 * P0.x); num.y = fmaf(v0, P1.y, v1 * P0.y);
  num.z = fmaf(v0, P1.z, v1 * P0.z); num.w = fmaf(v0, P1.w, v1 * P0.w);
  den.x = P0.x * P1.x; den.y = P0.y * P1.y;
  den.z = P0.z * P1.z; den.w = P0.w * P1.w;
  acc.x = fmaf(num.x, fast_rcp(den.x), acc.x);
  acc.y = fmaf(num.y, fast_rcp(den.y), acc.y);
  acc.z = fmaf(num.z, fast_rcp(den.z), acc.z);
  acc.w = fmaf(num.w, fast_rcp(den.w), acc.w);
  return acc;
}

// ---------------- K1: EWS = exp2(C*(q@W_s^T)) [b][t][h],
//                      EWHT = exp2(C*(enc@W_h^T)) TRANSPOSED [b][h][s] ------
// grid 512: 2 matrices x 128 row-tiles(32) x 2 col-halves(64). LDS ~51 KB ->
// 3 blocks/CU resident budget; 2x waves vs round 3 (was 1 block/CU at 83 KB).
__global__ __launch_bounds__(256) void bah_proj_kernel(
    const float* __restrict__ query, const float* __restrict__ enc,
    const float* __restrict__ W_s, const float* __restrict__ W_h,
    float* __restrict__ EWS, float* __restrict__ EWHT) {
  __shared__ __align__(16) float lds_w[64 * 132];   // 33.8 KB: one col-half
  __shared__ __align__(16) float lds_x[32 * 132];   // 16.9 KB; reused 64x33
  int blk = blockIdx.x;
  const bool is_wh = blk >= 256;
  const float* in = is_wh ? enc : query;
  const float* W  = is_wh ? W_h : W_s;
  blk &= 255;
  const int rb = blk >> 1, ch = blk & 1;
  const int r0 = rb * 32, c0 = ch * 64;
  const int tid = threadIdx.x;
  for (int i = tid; i < 2048; i += 256) {           // W: 64 rows x 32 float4
    int r = i >> 5, c4 = i & 31;
    *(float4*)(lds_w + r * 132 + c4 * 4) =
        *(const float4*)(W + (c0 + r) * 128 + c4 * 4);
  }
  for (int i = tid; i < 1024; i += 256) {           // x: 32 rows x 32 float4
    int r = i >> 5, c4 = i & 31;
    *(float4*)(lds_x + r * 132 + c4 * 4) =
        *(const float4*)(in + (r0 + r) * NH + c4 * 4);
  }
  __syncthreads();
  const int cg = tid & 31;         // cols c0+cg, c0+cg+32
  const int rg = tid >> 5;         // rows rg*4 .. rg*4+3
  float acc[4][2] = {{0,0},{0,0},{0,0},{0,0}};
  for (int k4 = 0; k4 < 32; ++k4) {
    float4 xa[4], wb[2];
    #pragma unroll
    for (int i = 0; i < 4; ++i)
      xa[i] = *(const float4*)(lds_x + (rg * 4 + i) * 132 + k4 * 4);
    #pragma unroll
    for (int m = 0; m < 2; ++m)
      wb[m] = *(const float4*)(lds_w + (cg + 32 * m) * 132 + k4 * 4);
    #pragma unroll
    for (int i = 0; i < 4; ++i)
      #pragma unroll
      for (int m = 0; m < 2; ++m)
        acc[i][m] += dot4(xa[i], wb[m]);
  }
  if (!is_wh) {
    #pragma unroll
    for (int i = 0; i < 4; ++i)
      #pragma unroll
      for (int m = 0; m < 2; ++m)    // lanes cg consecutive -> coalesced
        EWS[(r0 + rg * 4 + i) * NH + c0 + cg + 32 * m] =
            fast_exp2(C2LOG2E * acc[i][m]);
  } else {
    __syncthreads();                 // lds_x dead; reuse as 64x33 transpose
    #pragma unroll
    for (int i = 0; i < 4; ++i)
      #pragma unroll
      for (int m = 0; m < 2; ++m)
        lds_x[(cg + 32 * m) * 33 + rg * 4 + i] = fast_exp2(C2LOG2E * acc[i][m]);
    __syncthreads();
    const int b = r0 >> 9, sl0 = r0 & 511;
    const int s_lane = tid & 31, hr = tid >> 5;   // 8 groups x 8 h-rows
    #pragma unroll
    for (int j = 0; j < 8; ++j)      // lanes s consecutive -> coalesced 128B
      EWHT[b * NH * NS + (c0 + hr * 8 + j) * NS + sl0 + s_lane] =
          lds_x[(hr * 8 + j) * 33 + s_lane];
  }
}

// -------- K2a: scores. grid 1024 = (b, 8 t, 256 s); 4 blocks/CU ----------
// thread: tg=tid>>7 (4 t-rows), sp=tid&127 (2 contiguous s). F float2 loads,
// 2x t-redundancy. Fully-masked blocks zero-fill and exit.
__global__ __launch_bounds__(256) void bah_score_kernel(
    const float* __restrict__ EWS, const float* __restrict__ EWHT,
    const float* __restrict__ v, const int* __restrict__ src_len,
    float* __restrict__ SC) {
  __shared__ __align__(16) float lds_et[8 * 132];
  __shared__ __align__(16) float lds_v[128];
  const int blk = blockIdx.x;
  const int sh = blk & 1, tt8 = (blk >> 1) & 63, bb = blk >> 7;
  const int s0 = sh * 256, t0 = tt8 * 8;
  const int len = src_len[bb];
  const int tid = threadIdx.x;
  const int tg = tid >> 7, sp = tid & 127;
  const int sbase = s0 + sp * 2;
  float* scb = SC + (bb * NT + t0) * NS;
  if (len <= s0) {                   // block-uniform: whole s-range masked
    float2 z = {0.f, 0.f};
    #pragma unroll
    for (int tt = 0; tt < 4; ++tt)
      *(float2*)(scb + (tg * 4 + tt) * NS + sbase) = z;
    return;
  }
  if (tid < 32) *(float4*)(lds_v + tid * 4) = *(const float4*)(v + tid * 4);
  { int r = tid >> 5, c4 = tid & 31;   // 8x128 EWS rows = exactly 256 float4
    *(float4*)(lds_et + r * 132 + c4 * 4) =
        *(const float4*)(EWS + (bb * NT + t0 + r) * NH + c4 * 4); }
  __syncthreads();
  float V0 = 0.f;
  #pragma unroll
  for (int i = 0; i < 32; ++i) {
    float4 t4 = *(const float4*)(lds_v + i * 4);
    V0 += (t4.x + t4.y) + (t4.z + t4.w);
  }
  const float* et = lds_et + tg * 4 * 132;
  const float* fb = EWHT + bb * NH * NS + sbase;
  float2 acc2[4] = {{0,0},{0,0},{0,0},{0,0}};
  for (int ho = 0; ho < 16; ++ho) {
    const float* fh = fb + ho * 8 * NS;
    float2 F0 = *(const float2*)(fh + 0 * NS);   // coalesced 8B/lane (L2)
    float2 F1 = *(const float2*)(fh + 1 * NS);
    float2 F2 = *(const float2*)(fh + 2 * NS);
    float2 F3 = *(const float2*)(fh + 3 * NS);
    float2 F4 = *(const float2*)(fh + 4 * NS);
    float2 F5 = *(const float2*)(fh + 5 * NS);
    float2 F6 = *(const float2*)(fh + 6 * NS);
    float2 F7 = *(const float2*)(fh + 7 * NS);
    float4 va = *(const float4*)(lds_v + ho * 8);
    float4 vb = *(const float4*)(lds_v + ho * 8 + 4);
    #pragma unroll
    for (int tt = 0; tt < 4; ++tt) {
      float4 e0 = *(const float4*)(et + tt * 132 + ho * 8);     // broadcast
      float4 e1 = *(const float4*)(et + tt * 132 + ho * 8 + 4);
      acc2[tt] = pair_acc2(e0.x, e0.y, va.x, va.y, F0, F1, acc2[tt]);
      acc2[tt] = pair_acc2(e0.z, e0.w, va.z, va.w, F2, F3, acc2[tt]);
      acc2[tt] = pair_acc2(e1.x, e1.y, vb.x, vb.y, F4, F5, acc2[tt]);
      acc2[tt] = pair_acc2(e1.z, e1.w, vb.z, vb.w, F6, F7, acc2[tt]);
    }
  }
  #pragma unroll
  for (int tt = 0; tt < 4; ++tt) {
    float2 r;   // faithful quirk: masked scores ZEROED, still in softmax
    r.x = (sbase + 0 < len) ? fmaf(-2.f, acc2[tt].x, V0) : 0.f;
    r.y = (sbase + 1 < len) ? fmaf(-2.f, acc2[tt].y, V0) : 0.f;
    *(float2*)(scb + (tg * 4 + tt) * NS + sbase) = r;
  }
}

// -------- K2b: quirky softmax + ct per (b, 4 t-rows); grid 1024 -----------
__global__ __launch_bounds__(256) void bah_ctx_kernel(
    const float* __restrict__ SC, const float* __restrict__ enc,
    float* __restrict__ CT) {
  __shared__ __align__(16) float lds_sc[4 * 516];   // scores; later reduce buf
  __shared__ __align__(16) float lds_aT[512 * 4];   // attn transposed [s][t]
  __shared__ float red[16];
  const int tid = threadIdx.x;
  const int bb = blockIdx.x >> 7;
  const int t0 = (blockIdx.x & 127) * 4;
  for (int i = tid; i < 512; i += 256) {   // 4x512 scores, coalesced
    int r = i >> 7, c4 = i & 127;
    *(float4*)(lds_sc + r * 516 + c4 * 4) =
        *(const float4*)(SC + (bb * NT + t0 + r) * NS + c4 * 4);
  }
  __syncthreads();

  // ---- softmax per t-row; attn transposed into lds_aT ----
  const int t = tid & 3;
  const int c = tid >> 2;       // 0..63, 8 strided s values each
  const int wv = tid >> 6;
  float pv[8];
  float mx = -3.4e38f;
  #pragma unroll
  for (int k = 0; k < 8; ++k) {
    pv[k] = lds_sc[t * 516 + c + 64 * k];
    mx = fmaxf(mx, pv[k]);
  }
  #pragma unroll
  for (int msk = 4; msk <= 32; msk <<= 1)
    mx = fmaxf(mx, __shfl_xor(mx, msk, 64));
  if ((tid & 63) < 4) red[wv * 4 + t] = mx;
  __syncthreads();
  mx = fmaxf(fmaxf(red[t], red[4 + t]), fmaxf(red[8 + t], red[12 + t]));
  __syncthreads();
  float sum = 0.f;
  #pragma unroll
  for (int k = 0; k < 8; ++k) {
    pv[k] = fast_exp2((pv[k] - mx) * 1.4426950408889634f);
    sum += pv[k];
  }
  #pragma unroll
  for (int msk = 4; msk <= 32; msk <<= 1)
    sum += __shfl_xor(sum, msk, 64);
  if ((tid & 63) < 4) red[wv * 4 + t] = sum;
  __syncthreads();
  sum = (red[t] + red[4 + t]) + (red[8 + t] + red[12 + t]);
  const float rd = fast_rcp(sum);
  #pragma unroll
  for (int k = 0; k < 8; ++k)       // word = 4c+256k+t: consecutive per wave
    lds_aT[(c + 64 * k) * 4 + t] = pv[k] * rd;
  __syncthreads();

  // ---- ct[t][:] = sum_s attn[t][s] * enc[s][:] ----
  const int hg = tid & 31, sg = tid >> 5;   // 8 s-groups x 64 s
  float4 a4[4] = {{0,0,0,0},{0,0,0,0},{0,0,0,0},{0,0,0,0}};
  const float* eb = enc + bb * NS * NH + hg * 4;
  for (int k = 0; k < 64; ++k) {
    int s = sg * 64 + k;
    float4 e = *(const float4*)(eb + s * NH);       // coalesced global
    float4 w = *(const float4*)(lds_aT + s * 4);    // 4 t-weights, broadcast
    a4[0].x += w.x*e.x; a4[0].y += w.x*e.y; a4[0].z += w.x*e.z; a4[0].w += w.x*e.w;
    a4[1].x += w.y*e.x; a4[1].y += w.y*e.y; a4[1].z += w.y*e.z; a4[1].w += w.y*e.w;
    a4[2].x += w.z*e.x; a4[2].y += w.z*e.y; a4[2].z += w.z*e.z; a4[2].w += w.z*e.w;
    a4[3].x += w.w*e.x; a4[3].y += w.w*e.y; a4[3].z += w.w*e.z; a4[3].w += w.w*e.w;
  }
  #pragma unroll
  for (int i = 0; i < 4; ++i) {     // sg pairs within wave (lane^32)
    a4[i].x += __shfl_xor(a4[i].x, 32, 64);
    a4[i].y += __shfl_xor(a4[i].y, 32, 64);
    a4[i].z += __shfl_xor(a4[i].z, 32, 64);
    a4[i].w += __shfl_xor(a4[i].w, 32, 64);
  }
  float* lred = lds_sc;             // reuse: need 4*512 <= 4*516 floats
  const int lane = tid & 63;
  if (lane < 32) {
    #pragma unroll
    for (int i = 0; i < 4; ++i)
      *(float4*)(lred + wv * 512 + i * 128 + hg * 4) = a4[i];
  }
  __syncthreads();
  if (tid < 128) {
    int tt = tid >> 5, hh = tid & 31;
    float4 s0 = *(const float4*)(lred + 0 * 512 + tt * 128 + hh * 4);
    float4 s1 = *(const float4*)(lred + 1 * 512 + tt * 128 + hh * 4);
    float4 s2 = *(const float4*)(lred + 2 * 512 + tt * 128 + hh * 4);
    float4 s3 = *(const float4*)(lred + 3 * 512 + tt * 128 + hh * 4);
    float4 o;
    o.x = (s0.x + s1.x) + (s2.x + s3.x);
    o.y = (s0.y + s1.y) + (s2.y + s3.y);
    o.z = (s0.z + s1.z) + (s2.z + s3.z);
    o.w = (s0.w + s1.w) + (s2.w + s3.w);
    *(float4*)(CT + (bb * NT + t0 + tt) * NH + hh * 4) = o;
  }
}

// -------- Fallback fused K2 (round-2, proven) if ws too small for SC ------
__global__ __launch_bounds__(256, 4) void bah_attn_fused(
    const float* __restrict__ EWS, const float* __restrict__ EWHT,
    const float* __restrict__ v, const float* __restrict__ enc,
    const int* __restrict__ src_len, float* __restrict__ CT) {
  __shared__ __align__(16) float lds_et[8 * 132];
  __shared__ __align__(16) float lds_v[128];
  __shared__ __align__(16) float lds_sc[8 * 516];
  __shared__ __align__(16) float lds_aT[512 * 8];
  __shared__ float red[32];
  const int tid = threadIdx.x;
  const int bb = blockIdx.x >> 6;
  const int t0 = (blockIdx.x & 63) * 8;
  const int len = src_len[bb];
  if (tid < 32) *(float4*)(lds_v + tid * 4) = *(const float4*)(v + tid * 4);
  { int r = tid >> 5, c4 = tid & 31;
    *(float4*)(lds_et + r * 132 + c4 * 4) =
        *(const float4*)(EWS + (bb * NT + t0 + r) * NH + c4 * 4); }
  __syncthreads();
  float V0 = 0.f;
  #pragma unroll
  for (int i = 0; i < 32; ++i) {
    float4 t4 = *(const float4*)(lds_v + i * 4);
    V0 += (t4.x + t4.y) + (t4.z + t4.w);
  }
  const int tg = tid >> 7, sp = tid & 127;
  const float* et = lds_et + tg * 4 * 132;
  const float* fb = EWHT + bb * NH * NS + sp * 4;
  float4 acc4[4] = {{0,0,0,0},{0,0,0,0},{0,0,0,0},{0,0,0,0}};
  for (int ho = 0; ho < 16; ++ho) {
    const float* fh = fb + ho * 8 * NS;
    float4 F0 = *(const float4*)(fh + 0 * NS);
    float4 F1 = *(const float4*)(fh + 1 * NS);
    float4 F2 = *(const float4*)(fh + 2 * NS);
    float4 F3 = *(const float4*)(fh + 3 * NS);
    float4 F4 = *(const float4*)(fh + 4 * NS);
    float4 F5 = *(const float4*)(fh + 5 * NS);
    float4 F6 = *(const float4*)(fh + 6 * NS);
    float4 F7 = *(const float4*)(fh + 7 * NS);
    float4 va = *(const float4*)(lds_v + ho * 8);
    float4 vb = *(const float4*)(lds_v + ho * 8 + 4);
    #pragma unroll
    for (int tt = 0; tt < 4; ++tt) {
      float4 e0 = *(const float4*)(et + tt * 132 + ho * 8);
      float4 e1 = *(const float4*)(et + tt * 132 + ho * 8 + 4);
      acc4[tt] = pair_acc(e0.x, e0.y, va.x, va.y, F0, F1, acc4[tt]);
      acc4[tt] = pair_acc(e0.z, e0.w, va.z, va.w, F2, F3, acc4[tt]);
      acc4[tt] = pair_acc(e1.x, e1.y, vb.x, vb.y, F4, F5, acc4[tt]);
      acc4[tt] = pair_acc(e1.z, e1.w, vb.z, vb.w, F6, F7, acc4[tt]);
    }
  }
  const int sbase = sp * 4;
  #pragma unroll
  for (int tt = 0; tt < 4; ++tt) {
    float4 r;
    r.x = (sbase + 0 < len) ? fmaf(-2.f, acc4[tt].x, V0) : 0.f;
    r.y = (sbase + 1 < len) ? fmaf(-2.f, acc4[tt].y, V0) : 0.f;
    r.z = (sbase + 2 < len) ? fmaf(-2.f, acc4[tt].z, V0) : 0.f;
    r.w = (sbase + 3 < len) ? fmaf(-2.f, acc4[tt].w, V0) : 0.f;
    *(float4*)(lds_sc + (tg * 4 + tt) * 516 + sbase) = r;
  }
  __syncthreads();
  const int t = tid & 7;
  const int c = tid >> 3;
  const int wid = tid >> 6;
  float pv[16];
  float mx = -3.4e38f;
  #pragma unroll
  for (int k = 0; k < 16; ++k) {
    pv[k] = lds_sc[t * 516 + c + 32 * k];
    mx = fmaxf(mx, pv[k]);
  }
  #pragma unroll
  for (int msk = 8; msk <= 32; msk <<= 1)
    mx = fmaxf(mx, __shfl_xor(mx, msk, 64));
  if ((tid & 63) < 8) red[wid * 8 + t] = mx;
  __syncthreads();
  mx = fmaxf(fmaxf(red[t], red[8 + t]), fmaxf(red[16 + t], red[24 + t]));
  __syncthreads();
  float sum = 0.f;
  #pragma unroll
  for (int k = 0; k < 16; ++k) {
    pv[k] = fast_exp2((pv[k] - mx) * 1.4426950408889634f);
    sum += pv[k];
  }
  #pragma unroll
  for (int msk = 8; msk <= 32; msk <<= 1)
    sum += __shfl_xor(sum, msk, 64);
  if ((tid & 63) < 8) red[wid * 8 + t] = sum;
  __syncthreads();
  sum = (red[t] + red[8 + t]) + (red[16 + t] + red[24 + t]);
  const float rd = fast_rcp(sum);
  #pragma unroll
  for (int k = 0; k < 16; ++k)
    lds_aT[(c + 32 * k) * 8 + t] = pv[k] * rd;
  __syncthreads();
  const int hg = tid & 31, sg = tid >> 5;
  float4 a8[8] = {{0,0,0,0},{0,0,0,0},{0,0,0,0},{0,0,0,0},
                  {0,0,0,0},{0,0,0,0},{0,0,0,0},{0,0,0,0}};
  const float* eb = enc + bb * NS * NH + hg * 4;
  for (int k = 0; k < 64; ++k) {
    int s = sg * 64 + k;
    float4 e  = *(const float4*)(eb + s * NH);
    float4 w0 = *(const float4*)(lds_aT + s * 8);
    float4 w1 = *(const float4*)(lds_aT + s * 8 + 4);
    a8[0].x += w0.x*e.x; a8[0].y += w0.x*e.y; a8[0].z += w0.x*e.z; a8[0].w += w0.x*e.w;
    a8[1].x += w0.y*e.x; a8[1].y += w0.y*e.y; a8[1].z += w0.y*e.z; a8[1].w += w0.y*e.w;
    a8[2].x += w0.z*e.x; a8[2].y += w0.z*e.y; a8[2].z += w0.z*e.z; a8[2].w += w0.z*e.w;
    a8[3].x += w0.w*e.x; a8[3].y += w0.w*e.y; a8[3].z += w0.w*e.z; a8[3].w += w0.w*e.w;
    a8[4].x += w1.x*e.x; a8[4].y += w1.x*e.y; a8[4].z += w1.x*e.z; a8[4].w += w1.x*e.w;
    a8[5].x += w1.y*e.x; a8[5].y += w1.y*e.y; a8[5].z += w1.y*e.z; a8[5].w += w1.y*e.w;
    a8[6].x += w1.z*e.x; a8[6].y += w1.z*e.y; a8[6].z += w1.z*e.z; a8[6].w += w1.z*e.w;
    a8[7].x += w1.w*e.x; a8[7].y += w1.w*e.y; a8[7].z += w1.w*e.z; a8[7].w += w1.w*e.w;
  }
  #pragma unroll
  for (int i = 0; i < 8; ++i) {
    a8[i].x += __shfl_xor(a8[i].x, 32, 64);
    a8[i].y += __shfl_xor(a8[i].y, 32, 64);
    a8[i].z += __shfl_xor(a8[i].z, 32, 64);
    a8[i].w += __shfl_xor(a8[i].w, 32, 64);
  }
  float* lred = lds_sc;
  const int wv = tid >> 6, lane = tid & 63;
  if (lane < 32) {
    #pragma unroll
    for (int i = 0; i < 8; ++i)
      *(float4*)(lred + wv * 1024 + i * 128 + lane * 4) = a8[i];
  }
  __syncthreads();
  { int tt2 = tid >> 5, hh = tid & 31;
    float4 s0 = *(const float4*)(lred + 0 * 1024 + tt2 * 128 + hh * 4);
    float4 s1 = *(const float4*)(lred + 1 * 1024 + tt2 * 128 + hh * 4);
    float4 s2 = *(const float4*)(lred + 2 * 1024 + tt2 * 128 + hh * 4);
    float4 s3 = *(const float4*)(lred + 3 * 1024 + tt2 * 128 + hh * 4);
    float4 o;
    o.x = (s0.x + s1.x) + (s2.x + s3.x);
    o.y = (s0.y + s1.y) + (s2.y + s3.y);
    o.z = (s0.z + s1.z) + (s2.z + s3.z);
    o.w = (s0.w + s1.w) + (s2.w + s3.w);
    *(float4*)(CT + (bb * NT + t0 + tt2) * NH + hh * 4) = o;
  }
}

// -------- K3: out = tanh([ct, q] @ W_out^T + b) --------
// grid 512: 256 row-tiles(16) x 2 col-halves(64); W half in LDS, 2 k-passes.
__global__ __launch_bounds__(256) void bah_out_kernel(
    const float* __restrict__ CT, const float* __restrict__ query,
    const float* __restrict__ Wout, const float* __restrict__ bias,
    float* __restrict__ out) {
  __shared__ __align__(16) float lds_w[64 * 132];   // 33.8 KB
  __shared__ __align__(16) float lds_x[16 * 260];   // 16.6 KB
  const int rt = blockIdx.x >> 1, ch = blockIdx.x & 1;
  const int r0 = rt * 16, c0 = ch * 64;
  const int tid = threadIdx.x;
  for (int i = tid; i < 1024; i += 256) {    // 16 rows x 64 float4 (ct|q)
    int r = i >> 6, cc = (i & 63) * 4;
    float4 val = (cc < 128)
        ? *(const float4*)(CT + (r0 + r) * NH + cc)
        : *(const float4*)(query + (r0 + r) * NH + cc - 128);
    *(float4*)(lds_x + r * 260 + cc) = val;
  }
  const int cg = tid & 31;       // cols c0+cg, c0+cg+32
  const int rg = tid >> 5;       // rows rg*2, rg*2+1
  float acc[2][2] = {{0,0},{0,0}};
  for (int p = 0; p < 2; ++p) {
    __syncthreads();             // protect lds_w reload (and initial x stage)
    for (int i = tid; i < 2048; i += 256) {  // Wout[c0..c0+63][p*128..+127]
      int r = i >> 5, c4 = i & 31;
      *(float4*)(lds_w + r * 132 + c4 * 4) =
          *(const float4*)(Wout + (c0 + r) * 256 + p * 128 + c4 * 4);
    }
    __syncthreads();
    for (int k4 = 0; k4 < 32; ++k4) {
      float4 xa[2], wb[2];
      #pragma unroll
      for (int i = 0; i < 2; ++i)
        xa[i] = *(const float4*)(lds_x + (rg * 2 + i) * 260 + p * 128 + k4 * 4);
      #pragma unroll
      for (int m = 0; m < 2; ++m)
        wb[m] = *(const float4*)(lds_w + (cg + 32 * m) * 132 + k4 * 4);
      #pragma unroll
      for (int i = 0; i < 2; ++i)
        #pragma unroll
        for (int m = 0; m < 2; ++m)
          acc[i][m] += dot4(xa[i], wb[m]);
    }
  }
  #pragma unroll
  for (int i = 0; i < 2; ++i)
    #pragma unroll
    for (int m = 0; m < 2; ++m)
      out[(r0 + rg * 2 + i) * NH + c0 + cg + 32 * m] =
          fast_tanh(acc[i][m] + bias[c0 + cg + 32 * m]);
}

extern "C" void kernel_launch(void* const* d_in, const int* in_sizes, int n_in,
                              void* d_out, int out_size, void* d_ws, size_t ws_size,
                              hipStream_t stream) {
  const float* query = (const float*)d_in[0];
  const float* enc   = (const float*)d_in[1];
  const int*   slen  = (const int*)d_in[2];
  const float* W_h   = (const float*)d_in[3];
  const float* W_s   = (const float*)d_in[4];
  const float* v     = (const float*)d_in[5];
  const float* Woutw = (const float*)d_in[6];
  const float* Woutb = (const float*)d_in[7];
  float* out = (float*)d_out;

  float* ws = (float*)d_ws;
  float* EWS  = ws;                  // B*T*H   (2 MB)
  float* EWHT = ws + 524288;         // B*H*S   transposed (2 MB)
  float* CT   = ws + 1048576;        // B*T*H   (2 MB)
  float* SC   = ws + 1572864;        // B*T*S   (8 MB)
  const bool have_sc = ws_size >= (size_t)(1572864 + 2097152) * sizeof(float);

  bah_proj_kernel<<<512, 256, 0, stream>>>(query, enc, W_s, W_h, EWS, EWHT);
  if (have_sc) {
    bah_score_kernel<<<1024, 256, 0, stream>>>(EWS, EWHT, v, slen, SC);
    bah_ctx_kernel<<<1024, 256, 0, stream>>>(SC, enc, CT);
  } else {
    bah_attn_fused<<<512, 256, 0, stream>>>(EWS, EWHT, v, enc, slen, CT);
  }
  bah_out_kernel<<<512, 256, 0, stream>>>(CT, query, Woutw, Woutb, out);
}

// Round 5
// 128.202 us; speedup vs baseline: 1.5402x; 1.0535x over previous
//
#include <hip/hip_runtime.h>

#define NB 8
#define NT 512
#define NS 512
#define NH 128
#define C2LOG2E 2.8853900817779268f   // 2*log2(e): exp2(C*x) = e^(2x)

__device__ __forceinline__ float fast_exp2(float x) { return __builtin_amdgcn_exp2f(x); }
__device__ __forceinline__ float fast_rcp(float x)  { return __builtin_amdgcn_rcpf(x); }
__device__ __forceinline__ float fast_tanh(float x) {
  float e = fast_exp2(x * C2LOG2E);
  return 1.0f - 2.0f * fast_rcp(e + 1.0f);
}

__device__ __forceinline__ float dot4(float4 a, float4 b) {
  return (a.x * b.x + a.y * b.y) + (a.z * b.z + a.w * b.w);
}

// acc += v0/(e0*f0+1) + v1/(e1*f1+1) over 2 s values; 1 rcp per 2 h-elems.
__device__ __forceinline__ float2 pair_acc2(float e0, float e1, float v0, float v1,
                                            float2 f0, float2 f1, float2 acc) {
  float2 P0, P1, num, den;
  P0.x = fmaf(e0, f0.x, 1.0f); P0.y = fmaf(e0, f0.y, 1.0f);
  P1.x = fmaf(e1, f1.x, 1.0f); P1.y = fmaf(e1, f1.y, 1.0f);
  num.x = fmaf(v0, P1.x, v1 * P0.x); num.y = fmaf(v0, P1.y, v1 * P0.y);
  den.x = P0.x * P1.x; den.y = P0.y * P1.y;
  acc.x = fmaf(num.x, fast_rcp(den.x), acc.x);
  acc.y = fmaf(num.y, fast_rcp(den.y), acc.y);
  return acc;
}

// float4 variant for the fused fallback kernel.
__device__ __forceinline__ float4 pair_acc(float e0, float e1, float v0, float v1,
                                           float4 f0, float4 f1, float4 acc) {
  float4 P0, P1, num, den;
  P0.x = fmaf(e0, f0.x, 1.0f); P0.y = fmaf(e0, f0.y, 1.0f);
  P0.z = fmaf(e0, f0.z, 1.0f); P0.w = fmaf(e0, f0.w, 1.0f);
  P1.x = fmaf(e1, f1.x, 1.0f); P1.y = fmaf(e1, f1.y, 1.0f);
  P1.z = fmaf(e1, f1.z, 1.0f); P1.w = fmaf(e1, f1.w, 1.0f);
  num.x = fmaf(v0, P1.x, v1 * P0.x); num.y = fmaf(v0, P1.y, v1 * P0.y);
  num.z = fmaf(v0, P1.z, v1 * P0.z); num.w = fmaf(v0, P1.w, v1 * P0.w);
  den.x = P0.x * P1.x; den.y = P0.y * P1.y;
  den.z = P0.z * P1.z; den.w = P0.w * P1.w;
  acc.x = fmaf(num.x, fast_rcp(den.x), acc.x);
  acc.y = fmaf(num.y, fast_rcp(den.y), acc.y);
  acc.z = fmaf(num.z, fast_rcp(den.z), acc.z);
  acc.w = fmaf(num.w, fast_rcp(den.w), acc.w);
  return acc;
}

// ---------------- K1: EWS = exp2(C*(q@W_s^T)) [b][t][h],
//                      EWHT = exp2(C*(enc@W_h^T)) TRANSPOSED [b][h][s],
//                      + 32 repack blocks: WTP[k4][c][j] = Wout[c][4k4+j] ----
__global__ __launch_bounds__(256) void bah_proj_kernel(
    const float* __restrict__ query, const float* __restrict__ enc,
    const float* __restrict__ W_s, const float* __restrict__ W_h,
    const float* __restrict__ Wout,
    float* __restrict__ EWS, float* __restrict__ EWHT, float* __restrict__ WTP) {
  __shared__ __align__(16) float lds_w[64 * 132];   // 33.8 KB: one col-half
  __shared__ __align__(16) float lds_x[32 * 132];   // 16.9 KB; reused 64x33
  int blk = blockIdx.x;
  if (blk >= 512) {                 // Wout repack: 32 blocks x 256 thr x f4
    int g = (blk - 512) * 256 + threadIdx.x;        // g in [0, 8192)
    int c = g >> 6, k4 = g & 63;                    // coalesced read along k
    float4 w = *(const float4*)(Wout + c * 256 + k4 * 4);
    *(float4*)(WTP + k4 * 512 + c * 4) = w;         // scattered write (128KB)
    return;
  }
  const bool is_wh = blk >= 256;
  const float* in = is_wh ? enc : query;
  const float* W  = is_wh ? W_h : W_s;
  blk &= 255;
  const int rb = blk >> 1, ch = blk & 1;
  const int r0 = rb * 32, c0 = ch * 64;
  const int tid = threadIdx.x;
  for (int i = tid; i < 2048; i += 256) {           // W: 64 rows x 32 float4
    int r = i >> 5, c4 = i & 31;
    *(float4*)(lds_w + r * 132 + c4 * 4) =
        *(const float4*)(W + (c0 + r) * 128 + c4 * 4);
  }
  for (int i = tid; i < 1024; i += 256) {           // x: 32 rows x 32 float4
    int r = i >> 5, c4 = i & 31;
    *(float4*)(lds_x + r * 132 + c4 * 4) =
        *(const float4*)(in + (r0 + r) * NH + c4 * 4);
  }
  __syncthreads();
  const int cg = tid & 31;         // cols c0+cg, c0+cg+32
  const int rg = tid >> 5;         // rows rg*4 .. rg*4+3
  float acc[4][2] = {{0,0},{0,0},{0,0},{0,0}};
  for (int k4 = 0; k4 < 32; ++k4) {
    float4 xa[4], wb[2];
    #pragma unroll
    for (int i = 0; i < 4; ++i)
      xa[i] = *(const float4*)(lds_x + (rg * 4 + i) * 132 + k4 * 4);
    #pragma unroll
    for (int m = 0; m < 2; ++m)
      wb[m] = *(const float4*)(lds_w + (cg + 32 * m) * 132 + k4 * 4);
    #pragma unroll
    for (int i = 0; i < 4; ++i)
      #pragma unroll
      for (int m = 0; m < 2; ++m)
        acc[i][m] += dot4(xa[i], wb[m]);
  }
  if (!is_wh) {
    #pragma unroll
    for (int i = 0; i < 4; ++i)
      #pragma unroll
      for (int m = 0; m < 2; ++m)    // lanes cg consecutive -> coalesced
        EWS[(r0 + rg * 4 + i) * NH + c0 + cg + 32 * m] =
            fast_exp2(C2LOG2E * acc[i][m]);
  } else {
    __syncthreads();                 // lds_x dead; reuse as 64x33 transpose
    #pragma unroll
    for (int i = 0; i < 4; ++i)
      #pragma unroll
      for (int m = 0; m < 2; ++m)
        lds_x[(cg + 32 * m) * 33 + rg * 4 + i] = fast_exp2(C2LOG2E * acc[i][m]);
    __syncthreads();
    const int b = r0 >> 9, sl0 = r0 & 511;
    const int s_lane = tid & 31, hr = tid >> 5;   // 8 groups x 8 h-rows
    #pragma unroll
    for (int j = 0; j < 8; ++j)      // lanes s consecutive -> coalesced 128B
      EWHT[b * NH * NS + (c0 + hr * 8 + j) * NS + sl0 + s_lane] =
          lds_x[(hr * 8 + j) * 33 + s_lane];
  }
}

// -------- K2a: scores. grid 1024 = (b, 8 t, 256 s); h SPLIT across tg -----
// thread: tg=tid>>7 (h-half, wave-uniform), sp=tid&127 (2 contiguous s),
// owns ALL 8 t-rows -> F loaded once per (s,h), et reads amortized 8x.
__global__ __launch_bounds__(256) void bah_score_kernel(
    const float* __restrict__ EWS, const float* __restrict__ EWHT,
    const float* __restrict__ v, const int* __restrict__ src_len,
    float* __restrict__ SC) {
  __shared__ __align__(16) float lds_et[8 * 132];
  __shared__ __align__(16) float lds_v[128];
  __shared__ __align__(16) float lds_par[128 * 18];  // sp x (8t x 2s), pad 18
  const int blk = blockIdx.x;
  const int sh = blk & 1, tt8 = (blk >> 1) & 63, bb = blk >> 7;
  const int s0 = sh * 256, t0 = tt8 * 8;
  const int len = src_len[bb];
  const int tid = threadIdx.x;
  const int tg = tid >> 7, sp = tid & 127;
  const int sbase = s0 + sp * 2;
  float* scb = SC + (bb * NT + t0) * NS;
  if (len <= s0) {                   // block-uniform: whole s-range masked
    if (tg == 0) {
      float2 z = {0.f, 0.f};
      #pragma unroll
      for (int tt = 0; tt < 8; ++tt)
        *(float2*)(scb + tt * NS + sbase) = z;
    }
    return;
  }
  if (tid < 32) *(float4*)(lds_v + tid * 4) = *(const float4*)(v + tid * 4);
  { int r = tid >> 5, c4 = tid & 31;   // 8x128 EWS rows = exactly 256 float4
    *(float4*)(lds_et + r * 132 + c4 * 4) =
        *(const float4*)(EWS + (bb * NT + t0 + r) * NH + c4 * 4); }
  __syncthreads();
  const int h0 = tg * 64;
  const float* fb = EWHT + bb * NH * NS + h0 * NS + sbase;
  float2 acc2[8];
  #pragma unroll
  for (int i = 0; i < 8; ++i) { acc2[i].x = 0.f; acc2[i].y = 0.f; }
  for (int ho = 0; ho < 8; ++ho) {
    const float* fh = fb + ho * 8 * NS;
    float2 F0 = *(const float2*)(fh + 0 * NS);   // coalesced 8B/lane (L2)
    float2 F1 = *(const float2*)(fh + 1 * NS);
    float2 F2 = *(const float2*)(fh + 2 * NS);
    float2 F3 = *(const float2*)(fh + 3 * NS);
    float2 F4 = *(const float2*)(fh + 4 * NS);
    float2 F5 = *(const float2*)(fh + 5 * NS);
    float2 F6 = *(const float2*)(fh + 6 * NS);
    float2 F7 = *(const float2*)(fh + 7 * NS);
    float4 va = *(const float4*)(lds_v + h0 + ho * 8);
    float4 vb = *(const float4*)(lds_v + h0 + ho * 8 + 4);
    #pragma unroll
    for (int tt = 0; tt < 8; ++tt) {
      float4 e0 = *(const float4*)(lds_et + tt * 132 + h0 + ho * 8);  // bcast
      float4 e1 = *(const float4*)(lds_et + tt * 132 + h0 + ho * 8 + 4);
      acc2[tt] = pair_acc2(e0.x, e0.y, va.x, va.y, F0, F1, acc2[tt]);
      acc2[tt] = pair_acc2(e0.z, e0.w, va.z, va.w, F2, F3, acc2[tt]);
      acc2[tt] = pair_acc2(e1.x, e1.y, vb.x, vb.y, F4, F5, acc2[tt]);
      acc2[tt] = pair_acc2(e1.z, e1.w, vb.z, vb.w, F6, F7, acc2[tt]);
    }
  }
  if (tg == 1) {                     // publish h-half 1 partials
    #pragma unroll
    for (int tt = 0; tt < 8; ++tt)
      *(float2*)(lds_par + sp * 18 + tt * 2) = acc2[tt];
  }
  __syncthreads();
  if (tg == 0) {
    float V0 = 0.f;
    #pragma unroll
    for (int i = 0; i < 32; ++i) {
      float4 t4 = *(const float4*)(lds_v + i * 4);
      V0 += (t4.x + t4.y) + (t4.z + t4.w);
    }
    #pragma unroll
    for (int tt = 0; tt < 8; ++tt) {
      float2 oth = *(const float2*)(lds_par + sp * 18 + tt * 2);
      float sx = acc2[tt].x + oth.x;
      float sy = acc2[tt].y + oth.y;
      float2 r;  // faithful quirk: masked scores ZEROED, still in softmax
      r.x = (sbase + 0 < len) ? fmaf(-2.f, sx, V0) : 0.f;
      r.y = (sbase + 1 < len) ? fmaf(-2.f, sy, V0) : 0.f;
      *(float2*)(scb + tt * NS + sbase) = r;
    }
  }
}

// -------- K2b: quirky softmax + ct + OUT-GEMM fused; (b, 4 t), grid 1024 --
__global__ __launch_bounds__(256) void bah_ctx_out_kernel(
    const float* __restrict__ SC, const float* __restrict__ enc,
    const float* __restrict__ query, const float* __restrict__ WTP,
    const float* __restrict__ bias, float* __restrict__ out) {
  __shared__ __align__(16) float lds_sc[4 * 516];   // scores; later reduce buf
  __shared__ __align__(16) float lds_aT[512 * 4];   // attn T; later [ct|q] buf
  __shared__ float red[16];
  const int tid = threadIdx.x;
  const int bb = blockIdx.x >> 7;
  const int t0 = (blockIdx.x & 127) * 4;
  for (int i = tid; i < 512; i += 256) {   // 4x512 scores, coalesced
    int r = i >> 7, c4 = i & 127;
    *(float4*)(lds_sc + r * 516 + c4 * 4) =
        *(const float4*)(SC + (bb * NT + t0 + r) * NS + c4 * 4);
  }
  __syncthreads();

  // ---- softmax per t-row; attn transposed into lds_aT ----
  const int t = tid & 3;
  const int c = tid >> 2;       // 0..63, 8 strided s values each
  const int wv = tid >> 6;
  float pv[8];
  float mx = -3.4e38f;
  #pragma unroll
  for (int k = 0; k < 8; ++k) {
    pv[k] = lds_sc[t * 516 + c + 64 * k];
    mx = fmaxf(mx, pv[k]);
  }
  #pragma unroll
  for (int msk = 4; msk <= 32; msk <<= 1)
    mx = fmaxf(mx, __shfl_xor(mx, msk, 64));
  if ((tid & 63) < 4) red[wv * 4 + t] = mx;
  __syncthreads();
  mx = fmaxf(fmaxf(red[t], red[4 + t]), fmaxf(red[8 + t], red[12 + t]));
  __syncthreads();
  float sum = 0.f;
  #pragma unroll
  for (int k = 0; k < 8; ++k) {
    pv[k] = fast_exp2((pv[k] - mx) * 1.4426950408889634f);
    sum += pv[k];
  }
  #pragma unroll
  for (int msk = 4; msk <= 32; msk <<= 1)
    sum += __shfl_xor(sum, msk, 64);
  if ((tid & 63) < 4) red[wv * 4 + t] = sum;
  __syncthreads();
  sum = (red[t] + red[4 + t]) + (red[8 + t] + red[12 + t]);
  const float rd = fast_rcp(sum);
  #pragma unroll
  for (int k = 0; k < 8; ++k)
    lds_aT[(c + 64 * k) * 4 + t] = pv[k] * rd;
  __syncthreads();

  // ---- ct[t][:] = sum_s attn[t][s] * enc[s][:] ----
  const int hg = tid & 31, sg = tid >> 5;   // 8 s-groups x 64 s
  float4 a4[4] = {{0,0,0,0},{0,0,0,0},{0,0,0,0},{0,0,0,0}};
  const float* eb = enc + bb * NS * NH + hg * 4;
  for (int k = 0; k < 64; ++k) {
    int s = sg * 64 + k;
    float4 e = *(const float4*)(eb + s * NH);       // coalesced global
    float4 w = *(const float4*)(lds_aT + s * 4);    // 4 t-weights, broadcast
    a4[0].x += w.x*e.x; a4[0].y += w.x*e.y; a4[0].z += w.x*e.z; a4[0].w += w.x*e.w;
    a4[1].x += w.y*e.x; a4[1].y += w.y*e.y; a4[1].z += w.y*e.z; a4[1].w += w.y*e.w;
    a4[2].x += w.z*e.x; a4[2].y += w.z*e.y; a4[2].z += w.z*e.z; a4[2].w += w.z*e.w;
    a4[3].x += w.w*e.x; a4[3].y += w.w*e.y; a4[3].z += w.w*e.z; a4[3].w += w.w*e.w;
  }
  #pragma unroll
  for (int i = 0; i < 4; ++i) {     // sg pairs within wave (lane^32)
    a4[i].x += __shfl_xor(a4[i].x, 32, 64);
    a4[i].y += __shfl_xor(a4[i].y, 32, 64);
    a4[i].z += __shfl_xor(a4[i].z, 32, 64);
    a4[i].w += __shfl_xor(a4[i].w, 32, 64);
  }
  float* lred = lds_sc;             // reuse: 4*512 <= 4*516 floats
  const int lane = tid & 63;
  if (lane < 32) {
    #pragma unroll
    for (int i = 0; i < 4; ++i)
      *(float4*)(lred + wv * 512 + i * 128 + hg * 4) = a4[i];
  }
  __syncthreads();
  if (tid < 128) {                  // ct -> LDS (lds_aT reused: [ct|q])
    int tt = tid >> 5, hh = tid & 31;
    float4 s0 = *(const float4*)(lred + 0 * 512 + tt * 128 + hh * 4);
    float4 s1 = *(const float4*)(lred + 1 * 512 + tt * 128 + hh * 4);
    float4 s2 = *(const float4*)(lred + 2 * 512 + tt * 128 + hh * 4);
    float4 s3 = *(const float4*)(lred + 3 * 512 + tt * 128 + hh * 4);
    float4 o;
    o.x = (s0.x + s1.x) + (s2.x + s3.x);
    o.y = (s0.y + s1.y) + (s2.y + s3.y);
    o.z = (s0.z + s1.z) + (s2.z + s3.z);
    o.w = (s0.w + s1.w) + (s2.w + s3.w);
    *(float4*)(lds_aT + tt * 128 + hh * 4) = o;
    *(float4*)(lds_aT + 512 + tt * 128 + hh * 4) =
        *(const float4*)(query + (bb * NT + t0 + tt) * NH + hh * 4);
  }
  __syncthreads();

  // ---- out[t][c] = tanh([ct|q] . Wout[c] + b[c]) via packed-T WTP ----
  // thread: cc=tid&127 (out col), th=tid>>7 -> t rows th*2, th*2+1.
  // WTP[k4*512 + cc*4] loads: lanes cc consecutive -> coalesced b128.
  const int cc = tid & 127, th = tid >> 7;
  const float* x0 = lds_aT + (th * 2) * 128;        // ct row (k<128)
  const float* x1 = x0 + 128;
  const float* y0 = lds_aT + 512 + (th * 2) * 128;  // q row (k>=128)
  const float* y1 = y0 + 128;
  float a0 = 0.f, a1 = 0.f;
  for (int k4 = 0; k4 < 32; ++k4) {                 // ct half
    float4 w = *(const float4*)(WTP + k4 * 512 + cc * 4);
    a0 += dot4(*(const float4*)(x0 + k4 * 4), w);
    a1 += dot4(*(const float4*)(x1 + k4 * 4), w);
  }
  for (int k4 = 32; k4 < 64; ++k4) {                // q half
    float4 w = *(const float4*)(WTP + k4 * 512 + cc * 4);
    a0 += dot4(*(const float4*)(y0 + (k4 - 32) * 4), w);
    a1 += dot4(*(const float4*)(y1 + (k4 - 32) * 4), w);
  }
  const float bc = bias[cc];
  float* ob = out + (bb * NT + t0 + th * 2) * NH;
  ob[cc]      = fast_tanh(a0 + bc);
  ob[NH + cc] = fast_tanh(a1 + bc);
}

// -------- Fallback fused K2 (round-2, proven) if ws too small for SC ------
__global__ __launch_bounds__(256, 4) void bah_attn_fused(
    const float* __restrict__ EWS, const float* __restrict__ EWHT,
    const float* __restrict__ v, const float* __restrict__ enc,
    const int* __restrict__ src_len, float* __restrict__ CT) {
  __shared__ __align__(16) float lds_et[8 * 132];
  __shared__ __align__(16) float lds_v[128];
  __shared__ __align__(16) float lds_sc[8 * 516];
  __shared__ __align__(16) float lds_aT[512 * 8];
  __shared__ float red[32];
  const int tid = threadIdx.x;
  const int bb = blockIdx.x >> 6;
  const int t0 = (blockIdx.x & 63) * 8;
  const int len = src_len[bb];
  if (tid < 32) *(float4*)(lds_v + tid * 4) = *(const float4*)(v + tid * 4);
  { int r = tid >> 5, c4 = tid & 31;
    *(float4*)(lds_et + r * 132 + c4 * 4) =
        *(const float4*)(EWS + (bb * NT + t0 + r) * NH + c4 * 4); }
  __syncthreads();
  float V0 = 0.f;
  #pragma unroll
  for (int i = 0; i < 32; ++i) {
    float4 t4 = *(const float4*)(lds_v + i * 4);
    V0 += (t4.x + t4.y) + (t4.z + t4.w);
  }
  const int tg = tid >> 7, sp = tid & 127;
  const float* et = lds_et + tg * 4 * 132;
  const float* fb = EWHT + bb * NH * NS + sp * 4;
  float4 acc4[4] = {{0,0,0,0},{0,0,0,0},{0,0,0,0},{0,0,0,0}};
  for (int ho = 0; ho < 16; ++ho) {
    const float* fh = fb + ho * 8 * NS;
    float4 F0 = *(const float4*)(fh + 0 * NS);
    float4 F1 = *(const float4*)(fh + 1 * NS);
    float4 F2 = *(const float4*)(fh + 2 * NS);
    float4 F3 = *(const float4*)(fh + 3 * NS);
    float4 F4 = *(const float4*)(fh + 4 * NS);
    float4 F5 = *(const float4*)(fh + 5 * NS);
    float4 F6 = *(const float4*)(fh + 6 * NS);
    float4 F7 = *(const float4*)(fh + 7 * NS);
    float4 va = *(const float4*)(lds_v + ho * 8);
    float4 vb = *(const float4*)(lds_v + ho * 8 + 4);
    #pragma unroll
    for (int tt = 0; tt < 4; ++tt) {
      float4 e0 = *(const float4*)(et + tt * 132 + ho * 8);
      float4 e1 = *(const float4*)(et + tt * 132 + ho * 8 + 4);
      acc4[tt] = pair_acc(e0.x, e0.y, va.x, va.y, F0, F1, acc4[tt]);
      acc4[tt] = pair_acc(e0.z, e0.w, va.z, va.w, F2, F3, acc4[tt]);
      acc4[tt] = pair_acc(e1.x, e1.y, vb.x, vb.y, F4, F5, acc4[tt]);
      acc4[tt] = pair_acc(e1.z, e1.w, vb.z, vb.w, F6, F7, acc4[tt]);
    }
  }
  const int sbase = sp * 4;
  #pragma unroll
  for (int tt = 0; tt < 4; ++tt) {
    float4 r;
    r.x = (sbase + 0 < len) ? fmaf(-2.f, acc4[tt].x, V0) : 0.f;
    r.y = (sbase + 1 < len) ? fmaf(-2.f, acc4[tt].y, V0) : 0.f;
    r.z = (sbase + 2 < len) ? fmaf(-2.f, acc4[tt].z, V0) : 0.f;
    r.w = (sbase + 3 < len) ? fmaf(-2.f, acc4[tt].w, V0) : 0.f;
    *(float4*)(lds_sc + (tg * 4 + tt) * 516 + sbase) = r;
  }
  __syncthreads();
  const int t = tid & 7;
  const int c = tid >> 3;
  const int wid = tid >> 6;
  float pv[16];
  float mx = -3.4e38f;
  #pragma unroll
  for (int k = 0; k < 16; ++k) {
    pv[k] = lds_sc[t * 516 + c + 32 * k];
    mx = fmaxf(mx, pv[k]);
  }
  #pragma unroll
  for (int msk = 8; msk <= 32; msk <<= 1)
    mx = fmaxf(mx, __shfl_xor(mx, msk, 64));
  if ((tid & 63) < 8) red[wid * 8 + t] = mx;
  __syncthreads();
  mx = fmaxf(fmaxf(red[t], red[8 + t]), fmaxf(red[16 + t], red[24 + t]));
  __syncthreads();
  float sum = 0.f;
  #pragma unroll
  for (int k = 0; k < 16; ++k) {
    pv[k] = fast_exp2((pv[k] - mx) * 1.4426950408889634f);
    sum += pv[k];
  }
  #pragma unroll
  for (int msk = 8; msk <= 32; msk <<= 1)
    sum += __shfl_xor(sum, msk, 64);
  if ((tid & 63) < 8) red[wid * 8 + t] = sum;
  __syncthreads();
  sum = (red[t] + red[8 + t]) + (red[16 + t] + red[24 + t]);
  const float rd = fast_rcp(sum);
  #pragma unroll
  for (int k = 0; k < 16; ++k)
    lds_aT[(c + 32 * k) * 8 + t] = pv[k] * rd;
  __syncthreads();
  const int hg = tid & 31, sg = tid >> 5;
  float4 a8[8] = {{0,0,0,0},{0,0,0,0},{0,0,0,0},{0,0,0,0},
                  {0,0,0,0},{0,0,0,0},{0,0,0,0},{0,0,0,0}};
  const float* eb = enc + bb * NS * NH + hg * 4;
  for (int k = 0; k < 64; ++k) {
    int s = sg * 64 + k;
    float4 e  = *(const float4*)(eb + s * NH);
    float4 w0 = *(const float4*)(lds_aT + s * 8);
    float4 w1 = *(const float4*)(lds_aT + s * 8 + 4);
    a8[0].x += w0.x*e.x; a8[0].y += w0.x*e.y; a8[0].z += w0.x*e.z; a8[0].w += w0.x*e.w;
    a8[1].x += w0.y*e.x; a8[1].y += w0.y*e.y; a8[1].z += w0.y*e.z; a8[1].w += w0.y*e.w;
    a8[2].x += w0.z*e.x; a8[2].y += w0.z*e.y; a8[2].z += w0.z*e.z; a8[2].w += w0.z*e.w;
    a8[3].x += w0.w*e.x; a8[3].y += w0.w*e.y; a8[3].z += w0.w*e.z; a8[3].w += w0.w*e.w;
    a8[4].x += w1.x*e.x; a8[4].y += w1.x*e.y; a8[4].z += w1.x*e.z; a8[4].w += w1.x*e.w;
    a8[5].x += w1.y*e.x; a8[5].y += w1.y*e.y; a8[5].z += w1.y*e.z; a8[5].w += w1.y*e.w;
    a8[6].x += w1.z*e.x; a8[6].y += w1.z*e.y; a8[6].z += w1.z*e.z; a8[6].w += w1.z*e.w;
    a8[7].x += w1.w*e.x; a8[7].y += w1.w*e.y; a8[7].z += w1.w*e.z; a8[7].w += w1.w*e.w;
  }
  #pragma unroll
  for (int i = 0; i < 8; ++i) {
    a8[i].x += __shfl_xor(a8[i].x, 32, 64);
    a8[i].y += __shfl_xor(a8[i].y, 32, 64);
    a8[i].z += __shfl_xor(a8[i].z, 32, 64);
    a8[i].w += __shfl_xor(a8[i].w, 32, 64);
  }
  float* lred = lds_sc;
  const int wv = tid >> 6, lane = tid & 63;
  if (lane < 32) {
    #pragma unroll
    for (int i = 0; i < 8; ++i)
      *(float4*)(lred + wv * 1024 + i * 128 + lane * 4) = a8[i];
  }
  __syncthreads();
  { int tt2 = tid >> 5, hh = tid & 31;
    float4 s0 = *(const float4*)(lred + 0 * 1024 + tt2 * 128 + hh * 4);
    float4 s1 = *(const float4*)(lred + 1 * 1024 + tt2 * 128 + hh * 4);
    float4 s2 = *(const float4*)(lred + 2 * 1024 + tt2 * 128 + hh * 4);
    float4 s3 = *(const float4*)(lred + 3 * 1024 + tt2 * 128 + hh * 4);
    float4 o;
    o.x = (s0.x + s1.x) + (s2.x + s3.x);
    o.y = (s0.y + s1.y) + (s2.y + s3.y);
    o.z = (s0.z + s1.z) + (s2.z + s3.z);
    o.w = (s0.w + s1.w) + (s2.w + s3.w);
    *(float4*)(CT + (bb * NT + t0 + tt2) * NH + hh * 4) = o;
  }
}

// -------- Fallback K3 (round-4, proven): out = tanh([ct,q]@Wout^T + b) ----
__global__ __launch_bounds__(256) void bah_out_kernel(
    const float* __restrict__ CT, const float* __restrict__ query,
    const float* __restrict__ Wout, const float* __restrict__ bias,
    float* __restrict__ out) {
  __shared__ __align__(16) float lds_w[64 * 132];
  __shared__ __align__(16) float lds_x[16 * 260];
  const int rt = blockIdx.x >> 1, ch = blockIdx.x & 1;
  const int r0 = rt * 16, c0 = ch * 64;
  const int tid = threadIdx.x;
  for (int i = tid; i < 1024; i += 256) {
    int r = i >> 6, cc = (i & 63) * 4;
    float4 val = (cc < 128)
        ? *(const float4*)(CT + (r0 + r) * NH + cc)
        : *(const float4*)(query + (r0 + r) * NH + cc - 128);
    *(float4*)(lds_x + r * 260 + cc) = val;
  }
  const int cg = tid & 31;
  const int rg = tid >> 5;
  float acc[2][2] = {{0,0},{0,0}};
  for (int p = 0; p < 2; ++p) {
    __syncthreads();
    for (int i = tid; i < 2048; i += 256) {
      int r = i >> 5, c4 = i & 31;
      *(float4*)(lds_w + r * 132 + c4 * 4) =
          *(const float4*)(Wout + (c0 + r) * 256 + p * 128 + c4 * 4);
    }
    __syncthreads();
    for (int k4 = 0; k4 < 32; ++k4) {
      float4 xa[2], wb[2];
      #pragma unroll
      for (int i = 0; i < 2; ++i)
        xa[i] = *(const float4*)(lds_x + (rg * 2 + i) * 260 + p * 128 + k4 * 4);
      #pragma unroll
      for (int m = 0; m < 2; ++m)
        wb[m] = *(const float4*)(lds_w + (cg + 32 * m) * 132 + k4 * 4);
      #pragma unroll
      for (int i = 0; i < 2; ++i)
        #pragma unroll
        for (int m = 0; m < 2; ++m)
          acc[i][m] += dot4(xa[i], wb[m]);
    }
  }
  #pragma unroll
  for (int i = 0; i < 2; ++i)
    #pragma unroll
    for (int m = 0; m < 2; ++m)
      out[(r0 + rg * 2 + i) * NH + c0 + cg + 32 * m] =
          fast_tanh(acc[i][m] + bias[c0 + cg + 32 * m]);
}

extern "C" void kernel_launch(void* const* d_in, const int* in_sizes, int n_in,
                              void* d_out, int out_size, void* d_ws, size_t ws_size,
                              hipStream_t stream) {
  const float* query = (const float*)d_in[0];
  const float* enc   = (const float*)d_in[1];
  const int*   slen  = (const int*)d_in[2];
  const float* W_h   = (const float*)d_in[3];
  const float* W_s   = (const float*)d_in[4];
  const float* v     = (const float*)d_in[5];
  const float* Woutw = (const float*)d_in[6];
  const float* Woutb = (const float*)d_in[7];
  float* out = (float*)d_out;

  float* ws = (float*)d_ws;
  float* EWS  = ws;                  // B*T*H   (2 MB)
  float* EWHT = ws + 524288;         // B*H*S   transposed (2 MB)
  float* CT   = ws + 1048576;        // B*T*H   (fallback only, 2 MB)
  float* SC   = ws + 1572864;        // B*T*S   (8 MB)
  float* WTP  = ws + 3670016;        // 256*128 packed Wout^T (128 KB)
  const bool have_sc =
      ws_size >= (size_t)(3670016 + 32768) * sizeof(float);

  bah_proj_kernel<<<544, 256, 0, stream>>>(query, enc, W_s, W_h, Woutw,
                                           EWS, EWHT, WTP);
  if (have_sc) {
    bah_score_kernel<<<1024, 256, 0, stream>>>(EWS, EWHT, v, slen, SC);
    bah_ctx_out_kernel<<<1024, 256, 0, stream>>>(SC, enc, query, WTP,
                                                 Woutb, out);
  } else {
    bah_attn_fused<<<512, 256, 0, stream>>>(EWS, EWHT, v, enc, slen, CT);
    bah_out_kernel<<<512, 256, 0, stream>>>(CT, query, Woutw, Woutb, out);
  }
}

// Round 6
// 119.948 us; speedup vs baseline: 1.6462x; 1.0688x over previous
//
#include <hip/hip_runtime.h>

#define NB 8
#define NT 512
#define NS 512
#define NH 128
#define C2LOG2E 2.8853900817779268f   // 2*log2(e): exp2(C*x) = e^(2x)

__device__ __forceinline__ float fast_exp2(float x) { return __builtin_amdgcn_exp2f(x); }
__device__ __forceinline__ float fast_rcp(float x)  { return __builtin_amdgcn_rcpf(x); }
__device__ __forceinline__ float fast_tanh(float x) {
  float e = fast_exp2(x * C2LOG2E);
  return 1.0f - 2.0f * fast_rcp(e + 1.0f);
}

__device__ __forceinline__ float dot4(float4 a, float4 b) {
  return (a.x * b.x + a.y * b.y) + (a.z * b.z + a.w * b.w);
}

// acc += v0/(e0*f0+1) + v1/(e1*f1+1) over 2 s values; 1 rcp per 2 h-elems.
__device__ __forceinline__ float2 pair_acc2(float e0, float e1, float v0, float v1,
                                            float2 f0, float2 f1, float2 acc) {
  float2 P0, P1, num, den;
  P0.x = fmaf(e0, f0.x, 1.0f); P0.y = fmaf(e0, f0.y, 1.0f);
  P1.x = fmaf(e1, f1.x, 1.0f); P1.y = fmaf(e1, f1.y, 1.0f);
  num.x = fmaf(v0, P1.x, v1 * P0.x); num.y = fmaf(v0, P1.y, v1 * P0.y);
  den.x = P0.x * P1.x; den.y = P0.y * P1.y;
  acc.x = fmaf(num.x, fast_rcp(den.x), acc.x);
  acc.y = fmaf(num.y, fast_rcp(den.y), acc.y);
  return acc;
}

// ---------------- K1: EWS = exp2(C*(q@W_s^T)) [b][t][h],
//                      EWHT = exp2(C*(enc@W_h^T)) TRANSPOSED [b][h][s],
//                      + 32 repack blocks: WTP[k4][c][j] = Wout[c][4k4+j] ----
__global__ __launch_bounds__(256) void bah_proj_kernel(
    const float* __restrict__ query, const float* __restrict__ enc,
    const float* __restrict__ W_s, const float* __restrict__ W_h,
    const float* __restrict__ Wout,
    float* __restrict__ EWS, float* __restrict__ EWHT, float* __restrict__ WTP) {
  __shared__ __align__(16) float lds_w[64 * 132];   // 33.8 KB: one col-half
  __shared__ __align__(16) float lds_x[32 * 132];   // 16.9 KB; reused 64x33
  int blk = blockIdx.x;
  if (blk >= 512) {                 // Wout repack: 32 blocks x 256 thr x f4
    int g = (blk - 512) * 256 + threadIdx.x;        // g in [0, 8192)
    int c = g >> 6, k4 = g & 63;                    // coalesced read along k
    float4 w = *(const float4*)(Wout + c * 256 + k4 * 4);
    *(float4*)(WTP + k4 * 512 + c * 4) = w;         // scattered write (128KB)
    return;
  }
  const bool is_wh = blk >= 256;
  const float* in = is_wh ? enc : query;
  const float* W  = is_wh ? W_h : W_s;
  blk &= 255;
  const int rb = blk >> 1, ch = blk & 1;
  const int r0 = rb * 32, c0 = ch * 64;
  const int tid = threadIdx.x;
  for (int i = tid; i < 2048; i += 256) {           // W: 64 rows x 32 float4
    int r = i >> 5, c4 = i & 31;
    *(float4*)(lds_w + r * 132 + c4 * 4) =
        *(const float4*)(W + (c0 + r) * 128 + c4 * 4);
  }
  for (int i = tid; i < 1024; i += 256) {           // x: 32 rows x 32 float4
    int r = i >> 5, c4 = i & 31;
    *(float4*)(lds_x + r * 132 + c4 * 4) =
        *(const float4*)(in + (r0 + r) * NH + c4 * 4);
  }
  __syncthreads();
  const int cg = tid & 31;         // cols c0+cg, c0+cg+32
  const int rg = tid >> 5;         // rows rg*4 .. rg*4+3
  float acc[4][2] = {{0,0},{0,0},{0,0},{0,0}};
  for (int k4 = 0; k4 < 32; ++k4) {
    float4 xa[4], wb[2];
    #pragma unroll
    for (int i = 0; i < 4; ++i)
      xa[i] = *(const float4*)(lds_x + (rg * 4 + i) * 132 + k4 * 4);
    #pragma unroll
    for (int m = 0; m < 2; ++m)
      wb[m] = *(const float4*)(lds_w + (cg + 32 * m) * 132 + k4 * 4);
    #pragma unroll
    for (int i = 0; i < 4; ++i)
      #pragma unroll
      for (int m = 0; m < 2; ++m)
        acc[i][m] += dot4(xa[i], wb[m]);
  }
  if (!is_wh) {
    #pragma unroll
    for (int i = 0; i < 4; ++i)
      #pragma unroll
      for (int m = 0; m < 2; ++m)    // lanes cg consecutive -> coalesced
        EWS[(r0 + rg * 4 + i) * NH + c0 + cg + 32 * m] =
            fast_exp2(C2LOG2E * acc[i][m]);
  } else {
    __syncthreads();                 // lds_x dead; reuse as 64x33 transpose
    #pragma unroll
    for (int i = 0; i < 4; ++i)
      #pragma unroll
      for (int m = 0; m < 2; ++m)
        lds_x[(cg + 32 * m) * 33 + rg * 4 + i] = fast_exp2(C2LOG2E * acc[i][m]);
    __syncthreads();
    const int b = r0 >> 9, sl0 = r0 & 511;
    const int s_lane = tid & 31, hr = tid >> 5;   // 8 groups x 8 h-rows
    #pragma unroll
    for (int j = 0; j < 8; ++j)      // lanes s consecutive -> coalesced 128B
      EWHT[b * NH * NS + (c0 + hr * 8 + j) * NS + sl0 + s_lane] =
          lds_x[(hr * 8 + j) * 33 + s_lane];
  }
}

// -------- K2: MEGA — scores + quirky softmax + ct + out, all in LDS -------
// 512 threads, grid 512 = (b, 8 t-rows). ~62 KB LDS -> 2 blocks/CU,
// 16 waves/CU = 4 waves/SIMD. Scores never touch global memory.
__global__ __launch_bounds__(512, 4) void bah_mega_kernel(
    const float* __restrict__ EWS, const float* __restrict__ EWHT,
    const float* __restrict__ v, const float* __restrict__ enc,
    const float* __restrict__ query, const float* __restrict__ WTP,
    const float* __restrict__ bias, const int* __restrict__ src_len,
    float* __restrict__ out) {
  // One LDS arena, phase-aliased (floats):
  //  [0,128)      s_v
  //  [128,1184)   s_et   8x132 EWS rows
  //  [1184,5280)  s_aT   attn transposed [s][t], 512x8
  //  [5280,9632)  s_par  256x17 h-split partials (phase B)
  //               lred = s_par..s_par+8192 (phase D; overlays par+sc)
  //  [9632,13760) s_sc   8x516 scores (phase B->C)
  //  [13760,15808) s_ctq [ct(8x128) | q(8x128)] for out phase
  //  [15808,15872) s_red softmax cross-wave buffer
  __shared__ __align__(16) float smem[15872];
  float* s_v   = smem;
  float* s_et  = smem + 128;
  float* s_aT  = smem + 1184;
  float* s_par = smem + 5280;
  float* s_sc  = smem + 9632;
  float* s_ctq = smem + 13760;
  float* s_red = smem + 15808;

  const int tid = threadIdx.x;
  const int bb = blockIdx.x >> 6;
  const int t0 = (blockIdx.x & 63) * 8;
  const int len = src_len[bb];

  if (tid < 32) *(float4*)(s_v + tid * 4) = *(const float4*)(v + tid * 4);
  if (tid < 256) {                     // 8x128 EWS rows = 256 float4
    int r = tid >> 5, c4 = tid & 31;
    *(float4*)(s_et + r * 132 + c4 * 4) =
        *(const float4*)(EWS + (bb * NT + t0 + r) * NH + c4 * 4);
  }
  __syncthreads();

  // ---- Phase B: scores. tg=tid>>8 (h-half), sp=tid&255 (2 contiguous s),
  // each thread owns all 8 t-rows. Wave-level skip of fully-masked s-spans.
  const int tg = tid >> 8, sp = tid & 255;
  const int sbase = sp * 2;
  const int h0 = tg * 64;
  float2 acc2[8];
  #pragma unroll
  for (int i = 0; i < 8; ++i) { acc2[i].x = 0.f; acc2[i].y = 0.f; }
  const int wave_s0 = (sp & ~63) * 2;     // wave-uniform start of 128-s span
  if (wave_s0 < len) {
    const float* fb = EWHT + bb * NH * NS + h0 * NS + sbase;
    for (int ho = 0; ho < 8; ++ho) {
      const float* fh = fb + ho * 8 * NS;
      float2 F0 = *(const float2*)(fh + 0 * NS);   // coalesced 8B/lane (L2)
      float2 F1 = *(const float2*)(fh + 1 * NS);
      float2 F2 = *(const float2*)(fh + 2 * NS);
      float2 F3 = *(const float2*)(fh + 3 * NS);
      float2 F4 = *(const float2*)(fh + 4 * NS);
      float2 F5 = *(const float2*)(fh + 5 * NS);
      float2 F6 = *(const float2*)(fh + 6 * NS);
      float2 F7 = *(const float2*)(fh + 7 * NS);
      float4 va = *(const float4*)(s_v + h0 + ho * 8);
      float4 vb = *(const float4*)(s_v + h0 + ho * 8 + 4);
      #pragma unroll
      for (int tt = 0; tt < 8; ++tt) {
        float4 e0 = *(const float4*)(s_et + tt * 132 + h0 + ho * 8);  // bcast
        float4 e1 = *(const float4*)(s_et + tt * 132 + h0 + ho * 8 + 4);
        acc2[tt] = pair_acc2(e0.x, e0.y, va.x, va.y, F0, F1, acc2[tt]);
        acc2[tt] = pair_acc2(e0.z, e0.w, va.z, va.w, F2, F3, acc2[tt]);
        acc2[tt] = pair_acc2(e1.x, e1.y, vb.x, vb.y, F4, F5, acc2[tt]);
        acc2[tt] = pair_acc2(e1.z, e1.w, vb.z, vb.w, F6, F7, acc2[tt]);
      }
    }
  }
  if (tg == 1) {                       // stride 17: gcd(17,32)=1, conflict-free
    #pragma unroll
    for (int tt = 0; tt < 8; ++tt)
      *(float2*)(s_par + sp * 17 + tt * 2) = acc2[tt];
  }
  __syncthreads();
  if (tg == 0) {
    float V0 = 0.f;
    #pragma unroll
    for (int i = 0; i < 32; ++i) {
      float4 t4 = *(const float4*)(s_v + i * 4);
      V0 += (t4.x + t4.y) + (t4.z + t4.w);
    }
    #pragma unroll
    for (int tt = 0; tt < 8; ++tt) {
      float2 oth = *(const float2*)(s_par + sp * 17 + tt * 2);
      float sx = acc2[tt].x + oth.x;
      float sy = acc2[tt].y + oth.y;
      float2 r;  // faithful quirk: masked scores ZEROED, still in softmax
      r.x = (sbase + 0 < len) ? fmaf(-2.f, sx, V0) : 0.f;
      r.y = (sbase + 1 < len) ? fmaf(-2.f, sy, V0) : 0.f;
      *(float2*)(s_sc + tt * 516 + sbase) = r;
    }
  }
  __syncthreads();

  // ---- Phase C: softmax per t-row; attn transposed into s_aT ----
  const int t = tid & 7;
  const int c = tid >> 3;       // 0..63, 8 strided s values each
  const int wv = tid >> 6;
  float pv[8];
  float mx = -3.4e38f;
  #pragma unroll
  for (int k = 0; k < 8; ++k) {
    pv[k] = s_sc[t * 516 + c + 64 * k];
    mx = fmaxf(mx, pv[k]);
  }
  #pragma unroll
  for (int msk = 8; msk <= 32; msk <<= 1)
    mx = fmaxf(mx, __shfl_xor(mx, msk, 64));
  if ((tid & 63) < 8) s_red[wv * 8 + t] = mx;
  __syncthreads();
  #pragma unroll
  for (int j = 1; j < 8; ++j) mx = fmaxf(mx, s_red[j * 8 + t]);
  mx = fmaxf(mx, s_red[t]);
  __syncthreads();              // all reads done before red is rewritten
  float sum = 0.f;
  #pragma unroll
  for (int k = 0; k < 8; ++k) {
    pv[k] = fast_exp2((pv[k] - mx) * 1.4426950408889634f);
    sum += pv[k];
  }
  #pragma unroll
  for (int msk = 8; msk <= 32; msk <<= 1)
    sum += __shfl_xor(sum, msk, 64);
  if ((tid & 63) < 8) s_red[wv * 8 + t] = sum;
  __syncthreads();
  sum = 0.f;
  #pragma unroll
  for (int j = 0; j < 8; ++j) sum += s_red[j * 8 + t];
  const float rd = fast_rcp(sum);
  #pragma unroll
  for (int k = 0; k < 8; ++k)   // word 8(c+64k)+t: consecutive per wave
    s_aT[(c + 64 * k) * 8 + t] = pv[k] * rd;
  __syncthreads();

  // ---- Phase D: ct[t][:] = sum_s attn[t][s] * enc[s][:] ----
  const int hg = tid & 31, sg = tid >> 5;   // 16 s-groups x 32 s
  float4 a8[8] = {{0,0,0,0},{0,0,0,0},{0,0,0,0},{0,0,0,0},
                  {0,0,0,0},{0,0,0,0},{0,0,0,0},{0,0,0,0}};
  const float* eb = enc + bb * NS * NH + hg * 4;
  for (int k = 0; k < 32; ++k) {
    int s = sg * 32 + k;
    float4 e  = *(const float4*)(eb + s * NH);      // coalesced global
    float4 w0 = *(const float4*)(s_aT + s * 8);     // 2 addrs/wave: free
    float4 w1 = *(const float4*)(s_aT + s * 8 + 4);
    a8[0].x += w0.x*e.x; a8[0].y += w0.x*e.y; a8[0].z += w0.x*e.z; a8[0].w += w0.x*e.w;
    a8[1].x += w0.y*e.x; a8[1].y += w0.y*e.y; a8[1].z += w0.y*e.z; a8[1].w += w0.y*e.w;
    a8[2].x += w0.z*e.x; a8[2].y += w0.z*e.y; a8[2].z += w0.z*e.z; a8[2].w += w0.z*e.w;
    a8[3].x += w0.w*e.x; a8[3].y += w0.w*e.y; a8[3].z += w0.w*e.z; a8[3].w += w0.w*e.w;
    a8[4].x += w1.x*e.x; a8[4].y += w1.x*e.y; a8[4].z += w1.x*e.z; a8[4].w += w1.x*e.w;
    a8[5].x += w1.y*e.x; a8[5].y += w1.y*e.y; a8[5].z += w1.y*e.z; a8[5].w += w1.y*e.w;
    a8[6].x += w1.z*e.x; a8[6].y += w1.z*e.y; a8[6].z += w1.z*e.z; a8[6].w += w1.z*e.w;
    a8[7].x += w1.w*e.x; a8[7].y += w1.w*e.y; a8[7].z += w1.w*e.z; a8[7].w += w1.w*e.w;
  }
  #pragma unroll
  for (int i = 0; i < 8; ++i) {     // sg pairs within wave (lane^32)
    a8[i].x += __shfl_xor(a8[i].x, 32, 64);
    a8[i].y += __shfl_xor(a8[i].y, 32, 64);
    a8[i].z += __shfl_xor(a8[i].z, 32, 64);
    a8[i].w += __shfl_xor(a8[i].w, 32, 64);
  }
  float* lred = s_par;              // overlays par+sc (both dead): 8192 floats
  if ((tid & 63) < 32) {
    #pragma unroll
    for (int i = 0; i < 8; ++i)
      *(float4*)(lred + wv * 1024 + i * 128 + hg * 4) = a8[i];
  }
  __syncthreads();
  if (tid < 256) {                  // final ct reduce -> s_ctq
    int tt = tid >> 5, hh = tid & 31;
    float4 o = {0.f, 0.f, 0.f, 0.f};
    #pragma unroll
    for (int j = 0; j < 8; ++j) {
      float4 p = *(const float4*)(lred + j * 1024 + tt * 128 + hh * 4);
      o.x += p.x; o.y += p.y; o.z += p.z; o.w += p.w;
    }
    *(float4*)(s_ctq + tt * 128 + hh * 4) = o;
  } else {                          // q rows -> s_ctq upper half
    int r = tid - 256;
    int tt = r >> 5, hh = r & 31;
    *(float4*)(s_ctq + 1024 + tt * 128 + hh * 4) =
        *(const float4*)(query + (bb * NT + t0 + tt) * NH + hh * 4);
  }
  __syncthreads();

  // ---- Phase E: out[t][c] = tanh([ct|q] . Wout[c] + b[c]) via WTP ----
  const int cc = tid & 127, th = tid >> 7;      // th: rows th*2, th*2+1
  const float* x0 = s_ctq + (th * 2) * 128;     // ct rows (broadcast reads)
  const float* x1 = x0 + 128;
  const float* y0 = s_ctq + 1024 + (th * 2) * 128;  // q rows
  const float* y1 = y0 + 128;
  float a0 = 0.f, a1 = 0.f;
  for (int k4 = 0; k4 < 32; ++k4) {             // ct half of K
    float4 w = *(const float4*)(WTP + k4 * 512 + cc * 4);  // coalesced b128
    a0 += dot4(*(const float4*)(x0 + k4 * 4), w);
    a1 += dot4(*(const float4*)(x1 + k4 * 4), w);
  }
  for (int k4 = 32; k4 < 64; ++k4) {            // q half of K
    float4 w = *(const float4*)(WTP + k4 * 512 + cc * 4);
    a0 += dot4(*(const float4*)(y0 + (k4 - 32) * 4), w);
    a1 += dot4(*(const float4*)(y1 + (k4 - 32) * 4), w);
  }
  const float bc = bias[cc];
  float* ob = out + (bb * NT + t0 + th * 2) * NH;
  ob[cc]      = fast_tanh(a0 + bc);
  ob[NH + cc] = fast_tanh(a1 + bc);
}

extern "C" void kernel_launch(void* const* d_in, const int* in_sizes, int n_in,
                              void* d_out, int out_size, void* d_ws, size_t ws_size,
                              hipStream_t stream) {
  const float* query = (const float*)d_in[0];
  const float* enc   = (const float*)d_in[1];
  const int*   slen  = (const int*)d_in[2];
  const float* W_h   = (const float*)d_in[3];
  const float* W_s   = (const float*)d_in[4];
  const float* v     = (const float*)d_in[5];
  const float* Woutw = (const float*)d_in[6];
  const float* Woutb = (const float*)d_in[7];
  float* out = (float*)d_out;

  float* ws = (float*)d_ws;
  float* EWS  = ws;                  // B*T*H   (2 MB)
  float* EWHT = ws + 524288;         // B*H*S   transposed (2 MB)
  float* WTP  = ws + 1048576;        // 64x512 packed Wout^T (128 KB)

  bah_proj_kernel<<<544, 256, 0, stream>>>(query, enc, W_s, W_h, Woutw,
                                           EWS, EWHT, WTP);
  bah_mega_kernel<<<512, 512, 0, stream>>>(EWS, EWHT, v, enc, query, WTP,
                                           Woutb, slen, out);
}

// Round 7
// 118.085 us; speedup vs baseline: 1.6721x; 1.0158x over previous
//
#include <hip/hip_runtime.h>

#define NB 8
#define NT 512
#define NS 512
#define NH 128
#define C2LOG2E 2.8853900817779268f   // 2*log2(e): exp2(C*x) = e^(2x)

__device__ __forceinline__ float fast_exp2(float x) { return __builtin_amdgcn_exp2f(x); }
__device__ __forceinline__ float fast_rcp(float x)  { return __builtin_amdgcn_rcpf(x); }
__device__ __forceinline__ float fast_tanh(float x) {
  float e = fast_exp2(x * C2LOG2E);
  return 1.0f - 2.0f * fast_rcp(e + 1.0f);
}

__device__ __forceinline__ float dot4(float4 a, float4 b) {
  return (a.x * b.x + a.y * b.y) + (a.z * b.z + a.w * b.w);
}

// acc += v0/(e0*f0+1) + v1/(e1*f1+1) over 2 s values; 1 rcp per 2 h-elems.
__device__ __forceinline__ float2 pair_acc2(float e0, float e1, float v0, float v1,
                                            float2 f0, float2 f1, float2 acc) {
  float2 P0, P1, num, den;
  P0.x = fmaf(e0, f0.x, 1.0f); P0.y = fmaf(e0, f0.y, 1.0f);
  P1.x = fmaf(e1, f1.x, 1.0f); P1.y = fmaf(e1, f1.y, 1.0f);
  num.x = fmaf(v0, P1.x, v1 * P0.x); num.y = fmaf(v0, P1.y, v1 * P0.y);
  den.x = P0.x * P1.x; den.y = P0.y * P1.y;
  acc.x = fmaf(num.x, fast_rcp(den.x), acc.x);
  acc.y = fmaf(num.y, fast_rcp(den.y), acc.y);
  return acc;
}

// ---------------- K1: four 4096x128x128 GEMMs ----------------
// set 0: EWS  = exp2(C*(q  @ W_s^T))            [b][t][h]
// set 1: EWHT = exp2(C*(enc@ W_h^T)) TRANSPOSED [b][h][s]
// set 2: ENCW = enc @ W1^T   (W1 = Wout[:, :128])        [b][s][c]
// set 3: QW2  = q @ W2^T + b (W2 = Wout[:, 128:])        [b][t][c]
// ct@W1^T = sum_s a[t][s]*ENCW[s]  => mega's D phase emits out directly.
__global__ __launch_bounds__(256) void bah_proj_kernel(
    const float* __restrict__ query, const float* __restrict__ enc,
    const float* __restrict__ W_s, const float* __restrict__ W_h,
    const float* __restrict__ Wout, const float* __restrict__ Woutb,
    float* __restrict__ EWS, float* __restrict__ EWHT,
    float* __restrict__ ENCW, float* __restrict__ QW2) {
  __shared__ __align__(16) float lds_w[64 * 132];   // 33.8 KB: one col-half
  __shared__ __align__(16) float lds_x[32 * 132];   // 16.9 KB; reused 64x33
  const int set = blockIdx.x >> 8;
  const int blk = blockIdx.x & 255;
  const int rb = blk >> 1, ch = blk & 1;
  const int r0 = rb * 32, c0 = ch * 64;
  const int tid = threadIdx.x;
  const float* in = (set == 1 || set == 2) ? enc : query;
  const float* Wb; int wst;
  if (set == 0)      { Wb = W_s;        wst = 128; }
  else if (set == 1) { Wb = W_h;        wst = 128; }
  else if (set == 2) { Wb = Wout;       wst = 256; }
  else               { Wb = Wout + 128; wst = 256; }
  for (int i = tid; i < 2048; i += 256) {           // W: 64 rows x 32 float4
    int r = i >> 5, c4 = i & 31;
    *(float4*)(lds_w + r * 132 + c4 * 4) =
        *(const float4*)(Wb + (c0 + r) * wst + c4 * 4);
  }
  for (int i = tid; i < 1024; i += 256) {           // x: 32 rows x 32 float4
    int r = i >> 5, c4 = i & 31;
    *(float4*)(lds_x + r * 132 + c4 * 4) =
        *(const float4*)(in + (r0 + r) * NH + c4 * 4);
  }
  __syncthreads();
  const int cg = tid & 31;         // cols c0+cg, c0+cg+32
  const int rg = tid >> 5;         // rows rg*4 .. rg*4+3
  float acc[4][2] = {{0,0},{0,0},{0,0},{0,0}};
  for (int k4 = 0; k4 < 32; ++k4) {
    float4 xa[4], wb[2];
    #pragma unroll
    for (int i = 0; i < 4; ++i)      // wave-uniform addr -> broadcast
      xa[i] = *(const float4*)(lds_x + (rg * 4 + i) * 132 + k4 * 4);
    #pragma unroll
    for (int m = 0; m < 2; ++m)      // bank = (cg+k4)%32 -> conflict-free
      wb[m] = *(const float4*)(lds_w + (cg + 32 * m) * 132 + k4 * 4);
    #pragma unroll
    for (int i = 0; i < 4; ++i)
      #pragma unroll
      for (int m = 0; m < 2; ++m)
        acc[i][m] += dot4(xa[i], wb[m]);
  }
  if (set == 0) {
    #pragma unroll
    for (int i = 0; i < 4; ++i)
      #pragma unroll
      for (int m = 0; m < 2; ++m)    // lanes cg consecutive -> coalesced
        EWS[(r0 + rg * 4 + i) * NH + c0 + cg + 32 * m] =
            fast_exp2(C2LOG2E * acc[i][m]);
  } else if (set == 1) {
    __syncthreads();                 // lds_x dead; reuse as 64x33 transpose
    #pragma unroll
    for (int i = 0; i < 4; ++i)
      #pragma unroll
      for (int m = 0; m < 2; ++m)
        lds_x[(cg + 32 * m) * 33 + rg * 4 + i] = fast_exp2(C2LOG2E * acc[i][m]);
    __syncthreads();
    const int b = r0 >> 9, sl0 = r0 & 511;
    const int s_lane = tid & 31, hr = tid >> 5;   // 8 groups x 8 h-rows
    #pragma unroll
    for (int j = 0; j < 8; ++j)      // lanes s consecutive -> coalesced 128B
      EWHT[b * NH * NS + (c0 + hr * 8 + j) * NS + sl0 + s_lane] =
          lds_x[(hr * 8 + j) * 33 + s_lane];
  } else if (set == 2) {
    #pragma unroll
    for (int i = 0; i < 4; ++i)
      #pragma unroll
      for (int m = 0; m < 2; ++m)
        ENCW[(r0 + rg * 4 + i) * NH + c0 + cg + 32 * m] = acc[i][m];
  } else {
    #pragma unroll
    for (int i = 0; i < 4; ++i)
      #pragma unroll
      for (int m = 0; m < 2; ++m) {
        int c = c0 + cg + 32 * m;    // bias folded here, not in mega
        QW2[(r0 + rg * 4 + i) * NH + c] = acc[i][m] + Woutb[c];
      }
  }
}

// -------- K2: MEGA — scores + quirky softmax + attn x ENCW -> out ---------
// 512 threads, grid 512 = (b, 8 t-rows). ~55 KB LDS -> 2 blocks/CU.
// Phase E is gone: D contracts attn against ENCW and adds QW2 (= qW2+bias).
__global__ __launch_bounds__(512) void bah_mega_kernel(
    const float* __restrict__ EWS, const float* __restrict__ EWHT,
    const float* __restrict__ v, const float* __restrict__ ENCW,
    const float* __restrict__ QW2, const int* __restrict__ src_len,
    float* __restrict__ out) {
  // Arena (floats): s_v[0,128) s_et[128,1184) s_aT[1184,5280)
  // s_par[5280,9632) s_sc[9632,13760) s_red[13760,13824).
  // lred (phase D) overlays s_par+s_sc (needs 8192 <= 8480).
  __shared__ __align__(16) float smem[13824];
  float* s_v   = smem;
  float* s_et  = smem + 128;
  float* s_aT  = smem + 1184;
  float* s_par = smem + 5280;
  float* s_sc  = smem + 9632;
  float* s_red = smem + 13760;

  const int tid = threadIdx.x;
  const int bb = blockIdx.x >> 6;
  const int t0 = (blockIdx.x & 63) * 8;
  const int len = src_len[bb];

  if (tid < 32) *(float4*)(s_v + tid * 4) = *(const float4*)(v + tid * 4);
  if (tid < 256) {                     // 8x128 EWS rows = 256 float4
    int r = tid >> 5, c4 = tid & 31;
    *(float4*)(s_et + r * 132 + c4 * 4) =
        *(const float4*)(EWS + (bb * NT + t0 + r) * NH + c4 * 4);
  }
  __syncthreads();

  // V0 = sum(v) via one float2 read + wave shuffles (all lanes get it)
  float V0;
  {
    float2 vv = *(const float2*)(s_v + (tid & 63) * 2);
    V0 = vv.x + vv.y;
    #pragma unroll
    for (int msk = 1; msk <= 32; msk <<= 1)
      V0 += __shfl_xor(V0, msk, 64);
  }

  // ---- Phase B: scores. tg=tid>>8 (h-half), sp=tid&255 (2 contiguous s),
  // each thread owns all 8 t-rows. Wave-level skip of fully-masked s-spans.
  const int tg = tid >> 8, sp = tid & 255;
  const int sbase = sp * 2;
  const int h0 = tg * 64;
  float2 acc2[8];
  #pragma unroll
  for (int i = 0; i < 8; ++i) { acc2[i].x = 0.f; acc2[i].y = 0.f; }
  const int wave_s0 = (sp & ~63) * 2;     // wave-uniform start of 128-s span
  if (wave_s0 < len) {
    const float* fb = EWHT + bb * NH * NS + h0 * NS + sbase;
    for (int ho = 0; ho < 8; ++ho) {
      const float* fh = fb + ho * 8 * NS;
      float2 F0 = *(const float2*)(fh + 0 * NS);   // coalesced 8B/lane (L2)
      float2 F1 = *(const float2*)(fh + 1 * NS);
      float2 F2 = *(const float2*)(fh + 2 * NS);
      float2 F3 = *(const float2*)(fh + 3 * NS);
      float2 F4 = *(const float2*)(fh + 4 * NS);
      float2 F5 = *(const float2*)(fh + 5 * NS);
      float2 F6 = *(const float2*)(fh + 6 * NS);
      float2 F7 = *(const float2*)(fh + 7 * NS);
      float4 va = *(const float4*)(s_v + h0 + ho * 8);
      float4 vb = *(const float4*)(s_v + h0 + ho * 8 + 4);
      #pragma unroll
      for (int tt = 0; tt < 8; ++tt) {
        float4 e0 = *(const float4*)(s_et + tt * 132 + h0 + ho * 8);  // bcast
        float4 e1 = *(const float4*)(s_et + tt * 132 + h0 + ho * 8 + 4);
        acc2[tt] = pair_acc2(e0.x, e0.y, va.x, va.y, F0, F1, acc2[tt]);
        acc2[tt] = pair_acc2(e0.z, e0.w, va.z, va.w, F2, F3, acc2[tt]);
        acc2[tt] = pair_acc2(e1.x, e1.y, vb.x, vb.y, F4, F5, acc2[tt]);
        acc2[tt] = pair_acc2(e1.z, e1.w, vb.z, vb.w, F6, F7, acc2[tt]);
      }
    }
  }
  if (tg == 1) {                       // stride 17: gcd(17,32)=1, conflict-free
    #pragma unroll
    for (int tt = 0; tt < 8; ++tt)
      *(float2*)(s_par + sp * 17 + tt * 2) = acc2[tt];
  }
  __syncthreads();
  if (tg == 0) {
    #pragma unroll
    for (int tt = 0; tt < 8; ++tt) {
      float2 oth = *(const float2*)(s_par + sp * 17 + tt * 2);
      float sx = acc2[tt].x + oth.x;
      float sy = acc2[tt].y + oth.y;
      float2 r;  // faithful quirk: masked scores ZEROED, still in softmax
      r.x = (sbase + 0 < len) ? fmaf(-2.f, sx, V0) : 0.f;
      r.y = (sbase + 1 < len) ? fmaf(-2.f, sy, V0) : 0.f;
      *(float2*)(s_sc + tt * 516 + sbase) = r;
    }
  }
  __syncthreads();

  // ---- Phase C: softmax per t-row; attn transposed into s_aT ----
  const int t = tid & 7;
  const int c = tid >> 3;       // 0..63, 8 strided s values each
  const int wv = tid >> 6;
  float pv[8];
  float mx = -3.4e38f;
  #pragma unroll
  for (int k = 0; k < 8; ++k) {
    pv[k] = s_sc[t * 516 + c + 64 * k];
    mx = fmaxf(mx, pv[k]);
  }
  #pragma unroll
  for (int msk = 8; msk <= 32; msk <<= 1)
    mx = fmaxf(mx, __shfl_xor(mx, msk, 64));
  if ((tid & 63) < 8) s_red[wv * 8 + t] = mx;
  __syncthreads();
  #pragma unroll
  for (int j = 1; j < 8; ++j) mx = fmaxf(mx, s_red[j * 8 + t]);
  mx = fmaxf(mx, s_red[t]);
  __syncthreads();              // all reads done before red is rewritten
  float sum = 0.f;
  #pragma unroll
  for (int k = 0; k < 8; ++k) {
    pv[k] = fast_exp2((pv[k] - mx) * 1.4426950408889634f);
    sum += pv[k];
  }
  #pragma unroll
  for (int msk = 8; msk <= 32; msk <<= 1)
    sum += __shfl_xor(sum, msk, 64);
  if ((tid & 63) < 8) s_red[wv * 8 + t] = sum;
  __syncthreads();
  sum = 0.f;
  #pragma unroll
  for (int j = 0; j < 8; ++j) sum += s_red[j * 8 + t];
  const float rd = fast_rcp(sum);
  #pragma unroll
  for (int k = 0; k < 8; ++k)   // word 8(c+64k)+t: consecutive per wave
    s_aT[(c + 64 * k) * 8 + t] = pv[k] * rd;
  __syncthreads();

  // ---- Phase D': pre_out[t][c] = sum_s attn[t][s] * ENCW[s][c] ----
  const int hg = tid & 31, sg = tid >> 5;   // 16 s-groups x 32 s
  float4 a8[8] = {{0,0,0,0},{0,0,0,0},{0,0,0,0},{0,0,0,0},
                  {0,0,0,0},{0,0,0,0},{0,0,0,0},{0,0,0,0}};
  const float* eb = ENCW + bb * NS * NH + hg * 4;
  for (int k = 0; k < 32; ++k) {
    int s = sg * 32 + k;
    float4 e  = *(const float4*)(eb + s * NH);      // coalesced global
    float4 w0 = *(const float4*)(s_aT + s * 8);     // 2 addrs/wave: free
    float4 w1 = *(const float4*)(s_aT + s * 8 + 4);
    a8[0].x += w0.x*e.x; a8[0].y += w0.x*e.y; a8[0].z += w0.x*e.z; a8[0].w += w0.x*e.w;
    a8[1].x += w0.y*e.x; a8[1].y += w0.y*e.y; a8[1].z += w0.y*e.z; a8[1].w += w0.y*e.w;
    a8[2].x += w0.z*e.x; a8[2].y += w0.z*e.y; a8[2].z += w0.z*e.z; a8[2].w += w0.z*e.w;
    a8[3].x += w0.w*e.x; a8[3].y += w0.w*e.y; a8[3].z += w0.w*e.z; a8[3].w += w0.w*e.w;
    a8[4].x += w1.x*e.x; a8[4].y += w1.x*e.y; a8[4].z += w1.x*e.z; a8[4].w += w1.x*e.w;
    a8[5].x += w1.y*e.x; a8[5].y += w1.y*e.y; a8[5].z += w1.y*e.z; a8[5].w += w1.y*e.w;
    a8[6].x += w1.z*e.x; a8[6].y += w1.z*e.y; a8[6].z += w1.z*e.z; a8[6].w += w1.z*e.w;
    a8[7].x += w1.w*e.x; a8[7].y += w1.w*e.y; a8[7].z += w1.w*e.z; a8[7].w += w1.w*e.w;
  }
  #pragma unroll
  for (int i = 0; i < 8; ++i) {     // sg pairs within wave (lane^32)
    a8[i].x += __shfl_xor(a8[i].x, 32, 64);
    a8[i].y += __shfl_xor(a8[i].y, 32, 64);
    a8[i].z += __shfl_xor(a8[i].z, 32, 64);
    a8[i].w += __shfl_xor(a8[i].w, 32, 64);
  }
  float* lred = s_par;              // overlays par+sc (both dead): 8192 fl
  if ((tid & 63) < 32) {
    #pragma unroll
    for (int i = 0; i < 8; ++i)
      *(float4*)(lred + wv * 1024 + i * 128 + hg * 4) = a8[i];
  }
  __syncthreads();
  if (tid < 256) {                  // final reduce + QW2 (has bias) + tanh
    int tt = tid >> 5, hh = tid & 31;
    float4 o = {0.f, 0.f, 0.f, 0.f};
    #pragma unroll
    for (int j = 0; j < 8; ++j) {
      float4 p = *(const float4*)(lred + j * 1024 + tt * 128 + hh * 4);
      o.x += p.x; o.y += p.y; o.z += p.z; o.w += p.w;
    }
    const int row = bb * NT + t0 + tt;
    float4 q4 = *(const float4*)(QW2 + row * NH + hh * 4);  // coalesced
    float4 r;
    r.x = fast_tanh(o.x + q4.x);
    r.y = fast_tanh(o.y + q4.y);
    r.z = fast_tanh(o.z + q4.z);
    r.w = fast_tanh(o.w + q4.w);
    *(float4*)(out + row * NH + hh * 4) = r;
  }
}

extern "C" void kernel_launch(void* const* d_in, const int* in_sizes, int n_in,
                              void* d_out, int out_size, void* d_ws, size_t ws_size,
                              hipStream_t stream) {
  const float* query = (const float*)d_in[0];
  const float* enc   = (const float*)d_in[1];
  const int*   slen  = (const int*)d_in[2];
  const float* W_h   = (const float*)d_in[3];
  const float* W_s   = (const float*)d_in[4];
  const float* v     = (const float*)d_in[5];
  const float* Woutw = (const float*)d_in[6];
  const float* Woutb = (const float*)d_in[7];
  float* out = (float*)d_out;

  float* ws = (float*)d_ws;
  float* EWS  = ws;                  // B*T*H (2 MB)
  float* EWHT = ws + 524288;         // B*H*S transposed (2 MB)
  float* ENCW = ws + 1048576;        // B*S*H = enc @ W1^T (2 MB)
  float* QW2  = ws + 1572864;        // B*T*H = q @ W2^T + bias (2 MB)

  bah_proj_kernel<<<1024, 256, 0, stream>>>(query, enc, W_s, W_h, Woutw,
                                            Woutb, EWS, EWHT, ENCW, QW2);
  bah_mega_kernel<<<512, 512, 0, stream>>>(EWS, EWHT, v, ENCW, QW2, slen, out);
}